// Round 4
// baseline (1009.918 us; speedup 1.0000x reference)
//
#include <hip/hip_runtime.h>
#include <hip/hip_bf16.h>

#define N_NODES 100000
#define N_EDGES 3200000
#define ET (N_EDGES + N_NODES)   // edges + self loops
#define F_IN 500
#define H1 8
#define C1 8
#define F1 64                    // H1*C1
#define C2 7

#define BSH 6                    // 64 nodes per bucket
#define NB ((N_NODES + 63) / 64) // 1563
#define CAP 6144                 // LDS edge capacity per bucket (avg ~2111)

// ---------------- CSR build: two-level bucketed counting sort ----------------
__global__ __launch_bounds__(256) void bucket_hist(const int* __restrict__ ei,
                                                   int* __restrict__ bcnt) {
    __shared__ int h[NB];
    for (int i = threadIdx.x; i < NB; i += 256) h[i] = 0;
    __syncthreads();
    for (int i = blockIdx.x * 256 + threadIdx.x; i < ET; i += gridDim.x * 256) {
        const int dst = (i < N_EDGES) ? ei[N_EDGES + i] : (i - N_EDGES);
        atomicAdd(&h[dst >> BSH], 1);
    }
    __syncthreads();
    for (int i = threadIdx.x; i < NB; i += 256)
        if (h[i]) atomicAdd(&bcnt[i], h[i]);
}

// single block: exclusive scan of 1563 bucket counts -> boff, bcur; rowptr[N]=ET
__global__ __launch_bounds__(1024) void bucket_scan(const int* __restrict__ bcnt,
                                                    int* __restrict__ boff,
                                                    int* __restrict__ bcur,
                                                    int* __restrict__ rowptr) {
    __shared__ int wsum[16];
    const int t = threadIdx.x;
    const int lane = t & 63;
    const int w = t >> 6;
    int running = 0;
    for (int t0 = 0; t0 < 2048; t0 += 1024) {
        const int i = t0 + t;
        const int v = (i < NB) ? bcnt[i] : 0;
        int sc = v;
#pragma unroll
        for (int d = 1; d < 64; d <<= 1) {
            int u = __shfl_up(sc, d);
            if (lane >= d) sc += u;
        }
        if (lane == 63) wsum[w] = sc;
        __syncthreads();
        if (t < 16) {
            int ws = wsum[t];
#pragma unroll
            for (int d = 1; d < 16; d <<= 1) {
                int u = __shfl_up(ws, d);
                if (t >= d) ws += u;
            }
            wsum[t] = ws;
        }
        __syncthreads();
        const int base = running + (w ? wsum[w - 1] : 0);
        if (i < NB) {
            const int excl = base + sc - v;
            boff[i] = excl;
            bcur[i] = excl;
        }
        const int tot = wsum[15];
        __syncthreads();
        running += tot;
    }
    if (t == 0) {
        boff[NB] = running;            // == ET
        rowptr[N_NODES] = running;
    }
}

// scatter packed (ldst<<17 | src) into bucket-contiguous regions
__global__ void bucket_fill(const int* __restrict__ ei, int* __restrict__ bcur,
                            unsigned int* __restrict__ ebuf) {
    const int i = blockIdx.x * blockDim.x + threadIdx.x;
    if (i >= ET) return;
    int src, dst;
    if (i < N_EDGES) { src = ei[i]; dst = ei[N_EDGES + i]; }
    else             { src = dst = i - N_EDGES; }
    const int b = dst >> BSH;
    const unsigned l = (unsigned)(dst & 63);
    const int pos = atomicAdd(&bcur[b], 1);
    ebuf[pos] = (unsigned)src | (l << 17);
}

// one block per bucket: LDS counting sort -> coalesced col write + rowptr
__global__ __launch_bounds__(256) void bucket_csr(const int* __restrict__ boff,
                                                  const unsigned int* __restrict__ ebuf,
                                                  int* __restrict__ col,
                                                  int* __restrict__ rowptr) {
    __shared__ unsigned int ebs[CAP];
    __shared__ int colb[CAP];
    __shared__ int hist[64], curs[64];
    const int b = blockIdx.x, t = threadIdx.x;
    const int e0 = boff[b], e1 = boff[b + 1];
    const int cnt = e1 - e0;
    if (t < 64) hist[t] = 0;
    __syncthreads();

    if (cnt <= CAP) {
        for (int i = t; i < cnt; i += 256) {
            const unsigned v = ebuf[e0 + i];
            ebs[i] = v;
            atomicAdd(&hist[v >> 17], 1);
        }
        __syncthreads();
        if (t < 64) {
            const int v = hist[t];
            int sc = v;
#pragma unroll
            for (int d = 1; d < 64; d <<= 1) {
                int u = __shfl_up(sc, d);
                if (t >= d) sc += u;
            }
            const int excl = sc - v;
            curs[t] = excl;
            const int n = (b << BSH) + t;
            if (n < N_NODES) rowptr[n] = e0 + excl;
        }
        __syncthreads();
        for (int i = t; i < cnt; i += 256) {
            const unsigned v = ebs[i];
            const int p = atomicAdd(&curs[v >> 17], 1);
            colb[p] = (int)(v & 0x1FFFFu);
        }
        __syncthreads();
        for (int i = t; i < cnt; i += 256) col[e0 + i] = colb[i];
    } else {
        // fallback (never for ~2111-avg buckets): direct global scatter
        for (int i = t; i < cnt; i += 256) atomicAdd(&hist[ebuf[e0 + i] >> 17], 1);
        __syncthreads();
        if (t < 64) {
            const int v = hist[t];
            int sc = v;
#pragma unroll
            for (int d = 1; d < 64; d <<= 1) {
                int u = __shfl_up(sc, d);
                if (t >= d) sc += u;
            }
            const int excl = sc - v;
            curs[t] = excl;
            const int n = (b << BSH) + t;
            if (n < N_NODES) rowptr[n] = e0 + excl;
        }
        __syncthreads();
        for (int i = t; i < cnt; i += 256) {
            const unsigned v = ebuf[e0 + i];
            const int p = atomicAdd(&curs[v >> 17], 1);
            col[e0 + p] = (int)(v & 0x1FFFFu);
        }
    }
}

// ---------------- layer 1 GEMM + attention coefficients ----------------
// block = 256 (4 waves); 32 rows; K chunked by 100; LDS double-buffered with
// register prefetch of the next chunk (global latency hides under FMA).
#define G1_ROWS 32
#define KC 100
__global__ __launch_bounds__(256) void gemm1_kernel(
    const float* __restrict__ x, const float* __restrict__ W1,
    const float* __restrict__ a_src, const float* __restrict__ a_dst,
    float* __restrict__ h1, float* __restrict__ as1, float* __restrict__ ad1)
{
    __shared__ float xs[2][G1_ROWS][KC];     // 25600 B
    const int tid  = threadIdx.x;
    const int lane = tid & 63;
    const int wave = tid >> 6;
    const int row0 = blockIdx.x * G1_ROWS;   // 100000 % 32 == 0
    const int rbase = wave * 8;
    const int crow = tid >> 3;               // copy: row, 8 threads per row
    const int cq   = tid & 7;
    const float4* __restrict__ xrow = (const float4*)(x + (size_t)(row0 + crow) * F_IN);

    float4 pa, pb, pc, pd;
    // prefetch chunk 0
    {
        const float4* s = xrow;              // chunk 0: elements [0,100)
        pa = s[cq]; pb = s[cq + 8]; pc = s[cq + 16];
        if (cq == 0) pd = s[24];
    }
    {
        float4* d = (float4*)&xs[0][crow][0];
        d[cq] = pa; d[cq + 8] = pb; d[cq + 16] = pc;
        if (cq == 0) d[24] = pd;
    }
    __syncthreads();

    float acc[8];
#pragma unroll
    for (int r = 0; r < 8; ++r) acc[r] = 0.f;

    for (int c = 0; c < 5; ++c) {
        if (c < 4) {                          // prefetch chunk c+1 into regs
            const float4* s = xrow + (c + 1) * (KC / 4);
            pa = s[cq]; pb = s[cq + 8]; pc = s[cq + 16];
            if (cq == 0) pd = s[24];
        }
        const float (* __restrict__ xb)[KC] = xs[c & 1];
        const float* wp = W1 + (c * KC) * F1 + lane;
#pragma unroll 5
        for (int k4 = 0; k4 < KC / 4; ++k4) {
            const float w0 = wp[0];
            const float w1 = wp[F1];
            const float w2 = wp[2 * F1];
            const float w3 = wp[3 * F1];
            wp += 4 * F1;
#pragma unroll
            for (int r = 0; r < 8; ++r) {
                const float4 xv = *(const float4*)&xb[rbase + r][k4 * 4];
                acc[r] = fmaf(xv.x, w0, acc[r]);
                acc[r] = fmaf(xv.y, w1, acc[r]);
                acc[r] = fmaf(xv.z, w2, acc[r]);
                acc[r] = fmaf(xv.w, w3, acc[r]);
            }
        }
        if (c < 4) {
            __syncthreads();
            float4* d = (float4*)&xs[(c + 1) & 1][crow][0];
            d[cq] = pa; d[cq + 8] = pb; d[cq + 16] = pc;
            if (cq == 0) d[24] = pd;
            __syncthreads();
        }
    }

    const float asc = a_src[lane];   // flat [h*8+c] == lane
    const float adc = a_dst[lane];
#pragma unroll
    for (int r = 0; r < 8; ++r) {
        const int gr = row0 + rbase + r;
        float ps = acc[r] * asc;
        float pd2 = acc[r] * adc;
#pragma unroll
        for (int m = 1; m < 8; m <<= 1) {
            ps += __shfl_xor(ps, m, 8);
            pd2 += __shfl_xor(pd2, m, 8);
        }
        h1[(size_t)gr * F1 + lane] = acc[r];
        if ((lane & 7) == 0) {
            as1[gr * H1 + (lane >> 3)] = ps;
            ad1[gr * H1 + (lane >> 3)] = pd2;
        }
    }
}

// ---------------- layer 1 aggregation: wave per node ----------------
__global__ __launch_bounds__(256) void agg1_kernel(
    const int* __restrict__ rowptr, const int* __restrict__ col,
    const float* __restrict__ h1, const float* __restrict__ as1,
    const float* __restrict__ ad1, const float* __restrict__ b1,
    float* __restrict__ hout)
{
    const int lane = threadIdx.x & 63;
    const int n = (blockIdx.x << 2) + (threadIdx.x >> 6);
    if (n >= N_NODES) return;
    const int h = lane >> 3;
    const int r0 = rowptr[n], r1 = rowptr[n + 1];
    const float adh = ad1[(n << 3) + h];

    float m = -1e30f, denom = 0.f, acc = 0.f;
    int j = r0;
    for (; j + 4 <= r1; j += 4) {
        const int s0 = col[j], s1 = col[j + 1], s2 = col[j + 2], s3 = col[j + 3];
        const float f0 = as1[(s0 << 3) + h], f1 = as1[(s1 << 3) + h];
        const float f2 = as1[(s2 << 3) + h], f3 = as1[(s3 << 3) + h];
        const float v0 = h1[(s0 << 6) + lane], v1 = h1[(s1 << 6) + lane];
        const float v2 = h1[(s2 << 6) + lane], v3 = h1[(s3 << 6) + lane];
        float e0 = f0 + adh; e0 = fmaxf(e0, 0.2f * e0);
        float e1 = f1 + adh; e1 = fmaxf(e1, 0.2f * e1);
        float e2 = f2 + adh; e2 = fmaxf(e2, 0.2f * e2);
        float e3 = f3 + adh; e3 = fmaxf(e3, 0.2f * e3);
        const float nm = fmaxf(fmaxf(m, fmaxf(e0, e1)), fmaxf(e2, e3));
        const float sc = __expf(m - nm);
        const float p0 = __expf(e0 - nm), p1 = __expf(e1 - nm);
        const float p2 = __expf(e2 - nm), p3 = __expf(e3 - nm);
        denom = fmaf(denom, sc, (p0 + p1) + (p2 + p3));
        acc *= sc;
        acc = fmaf(p0, v0, acc);
        acc = fmaf(p1, v1, acc);
        acc = fmaf(p2, v2, acc);
        acc = fmaf(p3, v3, acc);
        m = nm;
    }
    for (; j < r1; ++j) {
        const int s = col[j];
        float e = as1[(s << 3) + h] + adh;
        e = fmaxf(e, 0.2f * e);
        const float v = h1[(s << 6) + lane];
        const float nm = fmaxf(m, e);
        const float sc = __expf(m - nm);
        const float p = __expf(e - nm);
        denom = fmaf(denom, sc, p);
        acc = fmaf(p, v, acc * sc);
        m = nm;
    }
    hout[(n << 6) + lane] = acc / denom + b1[lane];
}

// ---------------- layer 2 GEMM + attention coefficients ----------------
__global__ __launch_bounds__(256) void gemm2_kernel(
    const float* __restrict__ hin, const float* __restrict__ W2,
    const float* __restrict__ a_src, const float* __restrict__ a_dst,
    float* __restrict__ h2p, float* __restrict__ as2, float* __restrict__ ad2)
{
    __shared__ float w2s[F1 * C2];
    __shared__ float as_s[C2], ad_s[C2];
    for (int i = threadIdx.x; i < F1 * C2; i += blockDim.x) w2s[i] = W2[i];
    if (threadIdx.x < C2) { as_s[threadIdx.x] = a_src[threadIdx.x]; ad_s[threadIdx.x] = a_dst[threadIdx.x]; }
    __syncthreads();

    int n = blockIdx.x * blockDim.x + threadIdx.x;
    if (n >= N_NODES) return;
    float acc[C2];
#pragma unroll
    for (int c = 0; c < C2; ++c) acc[c] = 0.f;
    const float* hp = hin + (size_t)n * F1;
    for (int k = 0; k < F1; k += 4) {
        const float4 hv = *(const float4*)(hp + k);
#pragma unroll
        for (int c = 0; c < C2; ++c) {
            acc[c] = fmaf(hv.x, w2s[(k + 0) * C2 + c], acc[c]);
            acc[c] = fmaf(hv.y, w2s[(k + 1) * C2 + c], acc[c]);
            acc[c] = fmaf(hv.z, w2s[(k + 2) * C2 + c], acc[c]);
            acc[c] = fmaf(hv.w, w2s[(k + 3) * C2 + c], acc[c]);
        }
    }
    float s = 0.f, d = 0.f;
#pragma unroll
    for (int c = 0; c < C2; ++c) {
        s = fmaf(acc[c], as_s[c], s);
        d = fmaf(acc[c], ad_s[c], d);
    }
    float4* o = (float4*)(h2p + (size_t)n * 8);
    o[0] = make_float4(acc[0], acc[1], acc[2], acc[3]);
    o[1] = make_float4(acc[4], acc[5], acc[6], 0.f);
    as2[n] = s;
    ad2[n] = d;
}

// ---------------- layer 2 aggregation + bias + log_softmax ----------------
__global__ __launch_bounds__(256) void agg2_kernel(
    const int* __restrict__ rowptr, const int* __restrict__ col,
    const float* __restrict__ h2p, const float* __restrict__ as2,
    const float* __restrict__ ad2, const float* __restrict__ b2,
    float* __restrict__ out)
{
    const int gq = (blockIdx.x * 256 + threadIdx.x) >> 2;   // node
    const int q = threadIdx.x & 3;
    if (gq >= N_NODES) return;
    const int r0 = rowptr[gq], r1 = rowptr[gq + 1];
    const float adn = ad2[gq];

    float m = -1e30f, denom = 0.f;
    float a0 = 0, a1 = 0, a2 = 0, a3 = 0, a4 = 0, a5 = 0, a6 = 0;
    for (int j = r0 + q; j < r1; j += 4) {
        const int s = col[j];
        float e = as2[s] + adn;
        e = fmaxf(e, 0.2f * e);
        const float4 va = *(const float4*)(h2p + (size_t)s * 8);
        const float4 vb = *(const float4*)(h2p + (size_t)s * 8 + 4);
        const float nm = fmaxf(m, e);
        const float sc = __expf(m - nm);
        const float ex = __expf(e - nm);
        denom = fmaf(denom, sc, ex);
        a0 = fmaf(ex, va.x, a0 * sc); a1 = fmaf(ex, va.y, a1 * sc);
        a2 = fmaf(ex, va.z, a2 * sc); a3 = fmaf(ex, va.w, a3 * sc);
        a4 = fmaf(ex, vb.x, a4 * sc); a5 = fmaf(ex, vb.y, a5 * sc);
        a6 = fmaf(ex, vb.z, a6 * sc);
        m = nm;
    }
#pragma unroll
    for (int d = 1; d < 4; d <<= 1) {
        const float om = __shfl_xor(m, d);
        const float od = __shfl_xor(denom, d);
        const float o0 = __shfl_xor(a0, d), o1 = __shfl_xor(a1, d);
        const float o2 = __shfl_xor(a2, d), o3 = __shfl_xor(a3, d);
        const float o4 = __shfl_xor(a4, d), o5 = __shfl_xor(a5, d);
        const float o6 = __shfl_xor(a6, d);
        const float nm = fmaxf(m, om);
        const float s1 = __expf(m - nm);
        const float s2 = __expf(om - nm);
        denom = denom * s1 + od * s2;
        a0 = a0 * s1 + o0 * s2; a1 = a1 * s1 + o1 * s2;
        a2 = a2 * s1 + o2 * s2; a3 = a3 * s1 + o3 * s2;
        a4 = a4 * s1 + o4 * s2; a5 = a5 * s1 + o5 * s2;
        a6 = a6 * s1 + o6 * s2;
        m = nm;
    }
    const float inv = 1.f / denom;
    float v0 = a0 * inv + b2[0], v1 = a1 * inv + b2[1];
    float v2 = a2 * inv + b2[2], v3 = a3 * inv + b2[3];
    float v4 = a4 * inv + b2[4], v5 = a5 * inv + b2[5];
    float v6 = a6 * inv + b2[6];
    float mx = fmaxf(fmaxf(fmaxf(v0, v1), fmaxf(v2, v3)), fmaxf(fmaxf(v4, v5), v6));
    const float se = __expf(v0 - mx) + __expf(v1 - mx) + __expf(v2 - mx) +
                     __expf(v3 - mx) + __expf(v4 - mx) + __expf(v5 - mx) +
                     __expf(v6 - mx);
    const float lse = __logf(se) + mx;
    const float wa = (q == 0) ? v0 : (q == 1) ? v1 : (q == 2) ? v2 : v3;
    const float wb = (q == 0) ? v4 : (q == 1) ? v5 : v6;
    out[gq * C2 + q] = wa - lse;
    if (q < 3) out[gq * C2 + q + 4] = wb - lse;
}

extern "C" void kernel_launch(void* const* d_in, const int* in_sizes, int n_in,
                              void* d_out, int out_size, void* d_ws, size_t ws_size,
                              hipStream_t stream) {
    const float* x      = (const float*)d_in[0];
    const int*   ei     = (const int*)  d_in[1];
    const float* W1     = (const float*)d_in[2];
    const float* a_src1 = (const float*)d_in[3];
    const float* a_dst1 = (const float*)d_in[4];
    const float* b1     = (const float*)d_in[5];
    const float* W2     = (const float*)d_in[6];
    const float* a_src2 = (const float*)d_in[7];
    const float* a_dst2 = (const float*)d_in[8];
    const float* b2     = (const float*)d_in[9];
    float* out = (float*)d_out;

    char* ws = (char*)d_ws;
    size_t off = 0;
    auto alloc = [&](size_t bytes) -> void* {
        void* p = ws + off;
        off += (bytes + 255) & ~(size_t)255;
        return p;
    };
    int*   rowptr = (int*)  alloc((N_NODES + 1) * sizeof(int));
    int*   bcnt   = (int*)  alloc((size_t)NB * sizeof(int));
    int*   boff   = (int*)  alloc((size_t)(NB + 1) * sizeof(int));
    int*   bcur   = (int*)  alloc((size_t)NB * sizeof(int));
    int*   colidx = (int*)  alloc((size_t)ET * sizeof(int));
    float* h1     = (float*)alloc((size_t)N_NODES * F1 * sizeof(float));
    float* as1    = (float*)alloc((size_t)N_NODES * H1 * sizeof(float));
    float* ad1    = (float*)alloc((size_t)N_NODES * H1 * sizeof(float));
    float* hout1  = (float*)alloc((size_t)N_NODES * F1 * sizeof(float));
    float* h2p    = (float*)alloc((size_t)N_NODES * 8 * sizeof(float));
    float* as2    = (float*)alloc((size_t)N_NODES * sizeof(float));
    float* ad2    = (float*)alloc((size_t)N_NODES * sizeof(float));
    // ebuf aliases h1 (dead before gemm1 writes h1): 13.2 MB < 25.6 MB
    unsigned int* ebuf = (unsigned int*)h1;

    hipMemsetAsync(bcnt, 0, (size_t)NB * sizeof(int), stream);
    bucket_hist<<<256, 256, 0, stream>>>(ei, bcnt);
    bucket_scan<<<1, 1024, 0, stream>>>(bcnt, boff, bcur, rowptr);
    bucket_fill<<<(ET + 255) / 256, 256, 0, stream>>>(ei, bcur, ebuf);
    bucket_csr<<<NB, 256, 0, stream>>>(boff, ebuf, colidx, rowptr);
    gemm1_kernel<<<N_NODES / G1_ROWS, 256, 0, stream>>>(x, W1, a_src1, a_dst1, h1, as1, ad1);
    agg1_kernel<<<(N_NODES + 3) / 4, 256, 0, stream>>>(rowptr, colidx, h1, as1, ad1, b1, hout1);
    gemm2_kernel<<<(N_NODES + 255) / 256, 256, 0, stream>>>(hout1, W2, a_src2, a_dst2, h2p, as2, ad2);
    agg2_kernel<<<(N_NODES * 4 + 255) / 256, 256, 0, stream>>>(rowptr, colidx, h2p, as2, ad2, b2, out);
}

// Round 5
// 606.964 us; speedup vs baseline: 1.6639x; 1.6639x over previous
//
#include <hip/hip_runtime.h>
#include <hip/hip_bf16.h>

#define N_NODES 100000
#define N_EDGES 3200000
#define ET (N_EDGES + N_NODES)   // edges + self loops
#define F_IN 500
#define H1 8
#define C1 8
#define F1 64                    // H1*C1
#define C2 7

#define BSH 6                    // 64 nodes per bucket
#define NB ((N_NODES + 63) / 64) // 1563
#define CAP 6144                 // LDS edge capacity per bucket (avg ~2111)
#define FB 64                    // partition blocks
#define FCHUNK ((ET + FB - 1) / FB)

// ---------------- CSR build: atomic-free 3-phase partition ----------------
// phase 1: per-block histogram -> private row of cntmat[FB][NB]
__global__ __launch_bounds__(1024) void fill_count(const int* __restrict__ ei,
                                                   int* __restrict__ cntmat) {
    __shared__ int hist[NB];
    const int t = threadIdx.x, blk = blockIdx.x;
    for (int i = t; i < NB; i += 1024) hist[i] = 0;
    __syncthreads();
    const int s0 = blk * FCHUNK;
    const int s1 = min(s0 + FCHUNK, ET);
    for (int i = s0 + t; i < s1; i += 1024) {
        const int dst = (i < N_EDGES) ? ei[N_EDGES + i] : (i - N_EDGES);
        atomicAdd(&hist[dst >> BSH], 1);
    }
    __syncthreads();
    int* row = cntmat + (size_t)blk * NB;
    for (int i = t; i < NB; i += 1024) row[i] = hist[i];
}

// phase 2 (single block): bucket totals -> exclusive scan -> boff;
// basemat[blk][b] = boff[b] + prefix over blocks of cntmat[:,b]
__global__ __launch_bounds__(1024) void scan2(const int* __restrict__ cntmat,
                                              int* __restrict__ boff,
                                              int* __restrict__ basemat,
                                              int* __restrict__ rowptr) {
    __shared__ int tot[2048];
    __shared__ int wsum[16];
    const int t = threadIdx.x;
    const int lane = t & 63;
    const int w = t >> 6;
    // column sums (coalesced across threads)
    for (int b = t; b < 2048; b += 1024) {
        int s = 0;
        if (b < NB)
            for (int j = 0; j < FB; ++j) s += cntmat[(size_t)j * NB + b];
        tot[b] = s;
    }
    __syncthreads();
    // block scan of tot[0..2047]
    int running = 0;
    for (int t0 = 0; t0 < 2048; t0 += 1024) {
        const int v = tot[t0 + t];
        int sc = v;
#pragma unroll
        for (int d = 1; d < 64; d <<= 1) {
            int u = __shfl_up(sc, d);
            if (lane >= d) sc += u;
        }
        if (lane == 63) wsum[w] = sc;
        __syncthreads();
        if (t < 16) {
            int ws = wsum[t];
#pragma unroll
            for (int d = 1; d < 16; d <<= 1) {
                int u = __shfl_up(ws, d);
                if (t >= d) ws += u;
            }
            wsum[t] = ws;
        }
        __syncthreads();
        const int excl = running + (w ? wsum[w - 1] : 0) + sc - v;
        if (t0 + t < NB) boff[t0 + t] = excl;
        const int tt = wsum[15];
        __syncthreads();          // wsum reads done before next-tile writes
        tot[t0 + t] = excl;
        running += tt;
    }
    if (t == 0) {
        boff[NB] = running;            // == ET
        rowptr[N_NODES] = running;
    }
    __syncthreads();
    // per-(block,bucket) bases (coalesced across threads)
    for (int b = t; b < NB; b += 1024) {
        int run = tot[b];
        for (int j = 0; j < FB; ++j) {
            basemat[(size_t)j * NB + b] = run;
            run += cntmat[(size_t)j * NB + b];
        }
    }
}

// phase 3: scatter into reserved chunks; LDS cursors, zero global atomics
__global__ __launch_bounds__(1024) void fill_scatter(const int* __restrict__ ei,
                                                     const int* __restrict__ basemat,
                                                     unsigned int* __restrict__ ebuf) {
    __shared__ int cur[NB];
    const int t = threadIdx.x, blk = blockIdx.x;
    const int* row = basemat + (size_t)blk * NB;
    for (int i = t; i < NB; i += 1024) cur[i] = row[i];
    __syncthreads();
    const int s0 = blk * FCHUNK;
    const int s1 = min(s0 + FCHUNK, ET);
    for (int i = s0 + t; i < s1; i += 1024) {
        int src, dst;
        if (i < N_EDGES) { src = ei[i]; dst = ei[N_EDGES + i]; }
        else             { src = dst = i - N_EDGES; }
        const int b = dst >> BSH;
        const int p = atomicAdd(&cur[b], 1);
        ebuf[p] = (unsigned)src | ((unsigned)(dst & 63) << 17);
    }
}

// one block per bucket: LDS counting sort -> coalesced col write + rowptr
__global__ __launch_bounds__(256) void bucket_csr(const int* __restrict__ boff,
                                                  const unsigned int* __restrict__ ebuf,
                                                  int* __restrict__ col,
                                                  int* __restrict__ rowptr) {
    __shared__ unsigned int ebs[CAP];
    __shared__ int colb[CAP];
    __shared__ int hist[64], curs[64];
    const int b = blockIdx.x, t = threadIdx.x;
    const int e0 = boff[b], e1 = boff[b + 1];
    const int cnt = e1 - e0;
    if (t < 64) hist[t] = 0;
    __syncthreads();

    if (cnt <= CAP) {
        for (int i = t; i < cnt; i += 256) {
            const unsigned v = ebuf[e0 + i];
            ebs[i] = v;
            atomicAdd(&hist[v >> 17], 1);
        }
        __syncthreads();
        if (t < 64) {
            const int v = hist[t];
            int sc = v;
#pragma unroll
            for (int d = 1; d < 64; d <<= 1) {
                int u = __shfl_up(sc, d);
                if (t >= d) sc += u;
            }
            const int excl = sc - v;
            curs[t] = excl;
            const int n = (b << BSH) + t;
            if (n < N_NODES) rowptr[n] = e0 + excl;
        }
        __syncthreads();
        for (int i = t; i < cnt; i += 256) {
            const unsigned v = ebs[i];
            const int p = atomicAdd(&curs[v >> 17], 1);
            colb[p] = (int)(v & 0x1FFFFu);
        }
        __syncthreads();
        for (int i = t; i < cnt; i += 256) col[e0 + i] = colb[i];
    } else {
        for (int i = t; i < cnt; i += 256) atomicAdd(&hist[ebuf[e0 + i] >> 17], 1);
        __syncthreads();
        if (t < 64) {
            const int v = hist[t];
            int sc = v;
#pragma unroll
            for (int d = 1; d < 64; d <<= 1) {
                int u = __shfl_up(sc, d);
                if (t >= d) sc += u;
            }
            const int excl = sc - v;
            curs[t] = excl;
            const int n = (b << BSH) + t;
            if (n < N_NODES) rowptr[n] = e0 + excl;
        }
        __syncthreads();
        for (int i = t; i < cnt; i += 256) {
            const unsigned v = ebuf[e0 + i];
            const int p = atomicAdd(&curs[v >> 17], 1);
            col[e0 + p] = (int)(v & 0x1FFFFu);
        }
    }
}

// ---------------- layer 1 GEMM + attention coefficients ----------------
#define G1_ROWS 32
#define KC 100
__global__ __launch_bounds__(256) void gemm1_kernel(
    const float* __restrict__ x, const float* __restrict__ W1,
    const float* __restrict__ a_src, const float* __restrict__ a_dst,
    float* __restrict__ h1, float* __restrict__ as1, float* __restrict__ ad1)
{
    __shared__ float xs[2][G1_ROWS][KC];     // 25600 B
    const int tid  = threadIdx.x;
    const int lane = tid & 63;
    const int wave = tid >> 6;
    const int row0 = blockIdx.x * G1_ROWS;   // 100000 % 32 == 0
    const int rbase = wave * 8;
    const int crow = tid >> 3;               // copy: row, 8 threads per row
    const int cq   = tid & 7;
    const float4* __restrict__ xrow = (const float4*)(x + (size_t)(row0 + crow) * F_IN);

    float4 pa, pb, pc, pd;
    {
        const float4* s = xrow;              // chunk 0
        pa = s[cq]; pb = s[cq + 8]; pc = s[cq + 16];
        if (cq == 0) pd = s[24];
    }
    {
        float4* d = (float4*)&xs[0][crow][0];
        d[cq] = pa; d[cq + 8] = pb; d[cq + 16] = pc;
        if (cq == 0) d[24] = pd;
    }
    __syncthreads();

    float acc[8];
#pragma unroll
    for (int r = 0; r < 8; ++r) acc[r] = 0.f;

    for (int c = 0; c < 5; ++c) {
        if (c < 4) {                          // prefetch chunk c+1 into regs
            const float4* s = xrow + (c + 1) * (KC / 4);
            pa = s[cq]; pb = s[cq + 8]; pc = s[cq + 16];
            if (cq == 0) pd = s[24];
        }
        const float (* __restrict__ xb)[KC] = xs[c & 1];
        const float* wp = W1 + (c * KC) * F1 + lane;
#pragma unroll 5
        for (int k4 = 0; k4 < KC / 4; ++k4) {
            const float w0 = wp[0];
            const float w1 = wp[F1];
            const float w2 = wp[2 * F1];
            const float w3 = wp[3 * F1];
            wp += 4 * F1;
#pragma unroll
            for (int r = 0; r < 8; ++r) {
                const float4 xv = *(const float4*)&xb[rbase + r][k4 * 4];
                acc[r] = fmaf(xv.x, w0, acc[r]);
                acc[r] = fmaf(xv.y, w1, acc[r]);
                acc[r] = fmaf(xv.z, w2, acc[r]);
                acc[r] = fmaf(xv.w, w3, acc[r]);
            }
        }
        if (c < 4) {
            __syncthreads();
            float4* d = (float4*)&xs[(c + 1) & 1][crow][0];
            d[cq] = pa; d[cq + 8] = pb; d[cq + 16] = pc;
            if (cq == 0) d[24] = pd;
            __syncthreads();
        }
    }

    const float asc = a_src[lane];   // flat [h*8+c] == lane
    const float adc = a_dst[lane];
#pragma unroll
    for (int r = 0; r < 8; ++r) {
        const int gr = row0 + rbase + r;
        float ps = acc[r] * asc;
        float pd2 = acc[r] * adc;
#pragma unroll
        for (int m = 1; m < 8; m <<= 1) {
            ps += __shfl_xor(ps, m, 8);
            pd2 += __shfl_xor(pd2, m, 8);
        }
        h1[(size_t)gr * F1 + lane] = acc[r];
        if ((lane & 7) == 0) {
            as1[gr * H1 + (lane >> 3)] = ps;
            ad1[gr * H1 + (lane >> 3)] = pd2;
        }
    }
}

// ---------------- layer 1 aggregation: wave per node ----------------
__global__ __launch_bounds__(256) void agg1_kernel(
    const int* __restrict__ rowptr, const int* __restrict__ col,
    const float* __restrict__ h1, const float* __restrict__ as1,
    const float* __restrict__ ad1, const float* __restrict__ b1,
    float* __restrict__ hout)
{
    const int lane = threadIdx.x & 63;
    const int n = (blockIdx.x << 2) + (threadIdx.x >> 6);
    if (n >= N_NODES) return;
    const int h = lane >> 3;
    const int r0 = rowptr[n], r1 = rowptr[n + 1];
    const float adh = ad1[(n << 3) + h];

    float m = -1e30f, denom = 0.f, acc = 0.f;
    int j = r0;
    for (; j + 4 <= r1; j += 4) {
        const int s0 = col[j], s1 = col[j + 1], s2 = col[j + 2], s3 = col[j + 3];
        const float f0 = as1[(s0 << 3) + h], f1 = as1[(s1 << 3) + h];
        const float f2 = as1[(s2 << 3) + h], f3 = as1[(s3 << 3) + h];
        const float v0 = h1[(s0 << 6) + lane], v1 = h1[(s1 << 6) + lane];
        const float v2 = h1[(s2 << 6) + lane], v3 = h1[(s3 << 6) + lane];
        float e0 = f0 + adh; e0 = fmaxf(e0, 0.2f * e0);
        float e1 = f1 + adh; e1 = fmaxf(e1, 0.2f * e1);
        float e2 = f2 + adh; e2 = fmaxf(e2, 0.2f * e2);
        float e3 = f3 + adh; e3 = fmaxf(e3, 0.2f * e3);
        const float nm = fmaxf(fmaxf(m, fmaxf(e0, e1)), fmaxf(e2, e3));
        const float sc = __expf(m - nm);
        const float p0 = __expf(e0 - nm), p1 = __expf(e1 - nm);
        const float p2 = __expf(e2 - nm), p3 = __expf(e3 - nm);
        denom = fmaf(denom, sc, (p0 + p1) + (p2 + p3));
        acc *= sc;
        acc = fmaf(p0, v0, acc);
        acc = fmaf(p1, v1, acc);
        acc = fmaf(p2, v2, acc);
        acc = fmaf(p3, v3, acc);
        m = nm;
    }
    for (; j < r1; ++j) {
        const int s = col[j];
        float e = as1[(s << 3) + h] + adh;
        e = fmaxf(e, 0.2f * e);
        const float v = h1[(s << 6) + lane];
        const float nm = fmaxf(m, e);
        const float sc = __expf(m - nm);
        const float p = __expf(e - nm);
        denom = fmaf(denom, sc, p);
        acc = fmaf(p, v, acc * sc);
        m = nm;
    }
    hout[(n << 6) + lane] = acc / denom + b1[lane];
}

// ---------------- layer 2 GEMM + attention coefficients ----------------
__global__ __launch_bounds__(256) void gemm2_kernel(
    const float* __restrict__ hin, const float* __restrict__ W2,
    const float* __restrict__ a_src, const float* __restrict__ a_dst,
    float* __restrict__ h2p, float* __restrict__ as2, float* __restrict__ ad2)
{
    __shared__ float w2s[F1 * C2];
    __shared__ float as_s[C2], ad_s[C2];
    for (int i = threadIdx.x; i < F1 * C2; i += blockDim.x) w2s[i] = W2[i];
    if (threadIdx.x < C2) { as_s[threadIdx.x] = a_src[threadIdx.x]; ad_s[threadIdx.x] = a_dst[threadIdx.x]; }
    __syncthreads();

    int n = blockIdx.x * blockDim.x + threadIdx.x;
    if (n >= N_NODES) return;
    float acc[C2];
#pragma unroll
    for (int c = 0; c < C2; ++c) acc[c] = 0.f;
    const float* hp = hin + (size_t)n * F1;
    for (int k = 0; k < F1; k += 4) {
        const float4 hv = *(const float4*)(hp + k);
#pragma unroll
        for (int c = 0; c < C2; ++c) {
            acc[c] = fmaf(hv.x, w2s[(k + 0) * C2 + c], acc[c]);
            acc[c] = fmaf(hv.y, w2s[(k + 1) * C2 + c], acc[c]);
            acc[c] = fmaf(hv.z, w2s[(k + 2) * C2 + c], acc[c]);
            acc[c] = fmaf(hv.w, w2s[(k + 3) * C2 + c], acc[c]);
        }
    }
    float s = 0.f, d = 0.f;
#pragma unroll
    for (int c = 0; c < C2; ++c) {
        s = fmaf(acc[c], as_s[c], s);
        d = fmaf(acc[c], ad_s[c], d);
    }
    float4* o = (float4*)(h2p + (size_t)n * 8);
    o[0] = make_float4(acc[0], acc[1], acc[2], acc[3]);
    o[1] = make_float4(acc[4], acc[5], acc[6], 0.f);
    as2[n] = s;
    ad2[n] = d;
}

// ---------------- layer 2 aggregation + bias + log_softmax ----------------
__global__ __launch_bounds__(256) void agg2_kernel(
    const int* __restrict__ rowptr, const int* __restrict__ col,
    const float* __restrict__ h2p, const float* __restrict__ as2,
    const float* __restrict__ ad2, const float* __restrict__ b2,
    float* __restrict__ out)
{
    const int gq = (blockIdx.x * 256 + threadIdx.x) >> 2;   // node
    const int q = threadIdx.x & 3;
    if (gq >= N_NODES) return;
    const int r0 = rowptr[gq], r1 = rowptr[gq + 1];
    const float adn = ad2[gq];

    float m = -1e30f, denom = 0.f;
    float a0 = 0, a1 = 0, a2 = 0, a3 = 0, a4 = 0, a5 = 0, a6 = 0;
    for (int j = r0 + q; j < r1; j += 4) {
        const int s = col[j];
        float e = as2[s] + adn;
        e = fmaxf(e, 0.2f * e);
        const float4 va = *(const float4*)(h2p + (size_t)s * 8);
        const float4 vb = *(const float4*)(h2p + (size_t)s * 8 + 4);
        const float nm = fmaxf(m, e);
        const float sc = __expf(m - nm);
        const float ex = __expf(e - nm);
        denom = fmaf(denom, sc, ex);
        a0 = fmaf(ex, va.x, a0 * sc); a1 = fmaf(ex, va.y, a1 * sc);
        a2 = fmaf(ex, va.z, a2 * sc); a3 = fmaf(ex, va.w, a3 * sc);
        a4 = fmaf(ex, vb.x, a4 * sc); a5 = fmaf(ex, vb.y, a5 * sc);
        a6 = fmaf(ex, vb.z, a6 * sc);
        m = nm;
    }
#pragma unroll
    for (int d = 1; d < 4; d <<= 1) {
        const float om = __shfl_xor(m, d);
        const float od = __shfl_xor(denom, d);
        const float o0 = __shfl_xor(a0, d), o1 = __shfl_xor(a1, d);
        const float o2 = __shfl_xor(a2, d), o3 = __shfl_xor(a3, d);
        const float o4 = __shfl_xor(a4, d), o5 = __shfl_xor(a5, d);
        const float o6 = __shfl_xor(a6, d);
        const float nm = fmaxf(m, om);
        const float s1 = __expf(m - nm);
        const float s2 = __expf(om - nm);
        denom = denom * s1 + od * s2;
        a0 = a0 * s1 + o0 * s2; a1 = a1 * s1 + o1 * s2;
        a2 = a2 * s1 + o2 * s2; a3 = a3 * s1 + o3 * s2;
        a4 = a4 * s1 + o4 * s2; a5 = a5 * s1 + o5 * s2;
        a6 = a6 * s1 + o6 * s2;
        m = nm;
    }
    const float inv = 1.f / denom;
    float v0 = a0 * inv + b2[0], v1 = a1 * inv + b2[1];
    float v2 = a2 * inv + b2[2], v3 = a3 * inv + b2[3];
    float v4 = a4 * inv + b2[4], v5 = a5 * inv + b2[5];
    float v6 = a6 * inv + b2[6];
    float mx = fmaxf(fmaxf(fmaxf(v0, v1), fmaxf(v2, v3)), fmaxf(fmaxf(v4, v5), v6));
    const float se = __expf(v0 - mx) + __expf(v1 - mx) + __expf(v2 - mx) +
                     __expf(v3 - mx) + __expf(v4 - mx) + __expf(v5 - mx) +
                     __expf(v6 - mx);
    const float lse = __logf(se) + mx;
    const float wa = (q == 0) ? v0 : (q == 1) ? v1 : (q == 2) ? v2 : v3;
    const float wb = (q == 0) ? v4 : (q == 1) ? v5 : v6;
    out[gq * C2 + q] = wa - lse;
    if (q < 3) out[gq * C2 + q + 4] = wb - lse;
}

extern "C" void kernel_launch(void* const* d_in, const int* in_sizes, int n_in,
                              void* d_out, int out_size, void* d_ws, size_t ws_size,
                              hipStream_t stream) {
    const float* x      = (const float*)d_in[0];
    const int*   ei     = (const int*)  d_in[1];
    const float* W1     = (const float*)d_in[2];
    const float* a_src1 = (const float*)d_in[3];
    const float* a_dst1 = (const float*)d_in[4];
    const float* b1     = (const float*)d_in[5];
    const float* W2     = (const float*)d_in[6];
    const float* a_src2 = (const float*)d_in[7];
    const float* a_dst2 = (const float*)d_in[8];
    const float* b2     = (const float*)d_in[9];
    float* out = (float*)d_out;

    char* ws = (char*)d_ws;
    size_t off = 0;
    auto alloc = [&](size_t bytes) -> void* {
        void* p = ws + off;
        off += (bytes + 255) & ~(size_t)255;
        return p;
    };
    int*   rowptr  = (int*)  alloc((N_NODES + 1) * sizeof(int));
    int*   boff    = (int*)  alloc((size_t)(NB + 1) * sizeof(int));
    int*   cntmat  = (int*)  alloc((size_t)FB * NB * sizeof(int));
    int*   basemat = (int*)  alloc((size_t)FB * NB * sizeof(int));
    int*   colidx  = (int*)  alloc((size_t)ET * sizeof(int));
    float* h1      = (float*)alloc((size_t)N_NODES * F1 * sizeof(float));
    float* as1     = (float*)alloc((size_t)N_NODES * H1 * sizeof(float));
    float* ad1     = (float*)alloc((size_t)N_NODES * H1 * sizeof(float));
    float* hout1   = (float*)alloc((size_t)N_NODES * F1 * sizeof(float));
    float* h2p     = (float*)alloc((size_t)N_NODES * 8 * sizeof(float));
    float* as2     = (float*)alloc((size_t)N_NODES * sizeof(float));
    float* ad2     = (float*)alloc((size_t)N_NODES * sizeof(float));
    // ebuf aliases h1 (dead before gemm1 writes h1): 13.2 MB < 25.6 MB
    unsigned int* ebuf = (unsigned int*)h1;

    fill_count<<<FB, 1024, 0, stream>>>(ei, cntmat);
    scan2<<<1, 1024, 0, stream>>>(cntmat, boff, basemat, rowptr);
    fill_scatter<<<FB, 1024, 0, stream>>>(ei, basemat, ebuf);
    bucket_csr<<<NB, 256, 0, stream>>>(boff, ebuf, colidx, rowptr);
    gemm1_kernel<<<N_NODES / G1_ROWS, 256, 0, stream>>>(x, W1, a_src1, a_dst1, h1, as1, ad1);
    agg1_kernel<<<(N_NODES + 3) / 4, 256, 0, stream>>>(rowptr, colidx, h1, as1, ad1, b1, hout1);
    gemm2_kernel<<<(N_NODES + 255) / 256, 256, 0, stream>>>(hout1, W2, a_src2, a_dst2, h2p, as2, ad2);
    agg2_kernel<<<(N_NODES * 4 + 255) / 256, 256, 0, stream>>>(rowptr, colidx, h2p, as2, ad2, b2, out);
}

// Round 6
// 513.211 us; speedup vs baseline: 1.9678x; 1.1827x over previous
//
#include <hip/hip_runtime.h>
#include <hip/hip_bf16.h>
#include <hip/hip_fp16.h>

#define N_NODES 100000
#define N_EDGES 3200000
#define ET (N_EDGES + N_NODES)   // edges + self loops
#define F_IN 500
#define H1 8
#define C1 8
#define F1 64                    // H1*C1
#define C2 7

#define BSH 6                    // 64 nodes per bucket
#define NB ((N_NODES + 63) / 64) // 1563
#define CAP 6144                 // LDS edge capacity per bucket (avg ~2111)
#define FB 64                    // partition blocks
#define FCHUNK ((ET + FB - 1) / FB)

// ---------------- CSR build: atomic-free 3-phase partition ----------------
__global__ __launch_bounds__(1024) void fill_count(const int* __restrict__ ei,
                                                   int* __restrict__ cntmat) {
    __shared__ int hist[NB];
    const int t = threadIdx.x, blk = blockIdx.x;
    for (int i = t; i < NB; i += 1024) hist[i] = 0;
    __syncthreads();
    const int s0 = blk * FCHUNK;
    const int s1 = min(s0 + FCHUNK, ET);
    for (int i = s0 + t; i < s1; i += 1024) {
        const int dst = (i < N_EDGES) ? ei[N_EDGES + i] : (i - N_EDGES);
        atomicAdd(&hist[dst >> BSH], 1);
    }
    __syncthreads();
    int* row = cntmat + (size_t)blk * NB;
    for (int i = t; i < NB; i += 1024) row[i] = hist[i];
}

__global__ __launch_bounds__(1024) void scan2(const int* __restrict__ cntmat,
                                              int* __restrict__ boff,
                                              int* __restrict__ basemat,
                                              int* __restrict__ rowptr) {
    __shared__ int tot[2048];
    __shared__ int wsum[16];
    const int t = threadIdx.x;
    const int lane = t & 63;
    const int w = t >> 6;
    for (int b = t; b < 2048; b += 1024) {
        int s = 0;
        if (b < NB)
            for (int j = 0; j < FB; ++j) s += cntmat[(size_t)j * NB + b];
        tot[b] = s;
    }
    __syncthreads();
    int running = 0;
    for (int t0 = 0; t0 < 2048; t0 += 1024) {
        const int v = tot[t0 + t];
        int sc = v;
#pragma unroll
        for (int d = 1; d < 64; d <<= 1) {
            int u = __shfl_up(sc, d);
            if (lane >= d) sc += u;
        }
        if (lane == 63) wsum[w] = sc;
        __syncthreads();
        if (t < 16) {
            int ws = wsum[t];
#pragma unroll
            for (int d = 1; d < 16; d <<= 1) {
                int u = __shfl_up(ws, d);
                if (t >= d) ws += u;
            }
            wsum[t] = ws;
        }
        __syncthreads();
        const int excl = running + (w ? wsum[w - 1] : 0) + sc - v;
        if (t0 + t < NB) boff[t0 + t] = excl;
        const int tt = wsum[15];
        __syncthreads();
        tot[t0 + t] = excl;
        running += tt;
    }
    if (t == 0) {
        boff[NB] = running;            // == ET
        rowptr[N_NODES] = running;
    }
    __syncthreads();
    for (int b = t; b < NB; b += 1024) {
        int run = tot[b];
        for (int j = 0; j < FB; ++j) {
            basemat[(size_t)j * NB + b] = run;
            run += cntmat[(size_t)j * NB + b];
        }
    }
}

__global__ __launch_bounds__(1024) void fill_scatter(const int* __restrict__ ei,
                                                     const int* __restrict__ basemat,
                                                     unsigned int* __restrict__ ebuf) {
    __shared__ int cur[NB];
    const int t = threadIdx.x, blk = blockIdx.x;
    const int* row = basemat + (size_t)blk * NB;
    for (int i = t; i < NB; i += 1024) cur[i] = row[i];
    __syncthreads();
    const int s0 = blk * FCHUNK;
    const int s1 = min(s0 + FCHUNK, ET);
    for (int i = s0 + t; i < s1; i += 1024) {
        int src, dst;
        if (i < N_EDGES) { src = ei[i]; dst = ei[N_EDGES + i]; }
        else             { src = dst = i - N_EDGES; }
        const int b = dst >> BSH;
        const int p = atomicAdd(&cur[b], 1);
        ebuf[p] = (unsigned)src | ((unsigned)(dst & 63) << 17);
    }
}

__global__ __launch_bounds__(256) void bucket_csr(const int* __restrict__ boff,
                                                  const unsigned int* __restrict__ ebuf,
                                                  int* __restrict__ col,
                                                  int* __restrict__ rowptr) {
    __shared__ unsigned int ebs[CAP];
    __shared__ int colb[CAP];
    __shared__ int hist[64], curs[64];
    const int b = blockIdx.x, t = threadIdx.x;
    const int e0 = boff[b], e1 = boff[b + 1];
    const int cnt = e1 - e0;
    if (t < 64) hist[t] = 0;
    __syncthreads();

    if (cnt <= CAP) {
        for (int i = t; i < cnt; i += 256) {
            const unsigned v = ebuf[e0 + i];
            ebs[i] = v;
            atomicAdd(&hist[v >> 17], 1);
        }
        __syncthreads();
        if (t < 64) {
            const int v = hist[t];
            int sc = v;
#pragma unroll
            for (int d = 1; d < 64; d <<= 1) {
                int u = __shfl_up(sc, d);
                if (t >= d) sc += u;
            }
            const int excl = sc - v;
            curs[t] = excl;
            const int n = (b << BSH) + t;
            if (n < N_NODES) rowptr[n] = e0 + excl;
        }
        __syncthreads();
        for (int i = t; i < cnt; i += 256) {
            const unsigned v = ebs[i];
            const int p = atomicAdd(&curs[v >> 17], 1);
            colb[p] = (int)(v & 0x1FFFFu);
        }
        __syncthreads();
        for (int i = t; i < cnt; i += 256) col[e0 + i] = colb[i];
    } else {
        for (int i = t; i < cnt; i += 256) atomicAdd(&hist[ebuf[e0 + i] >> 17], 1);
        __syncthreads();
        if (t < 64) {
            const int v = hist[t];
            int sc = v;
#pragma unroll
            for (int d = 1; d < 64; d <<= 1) {
                int u = __shfl_up(sc, d);
                if (t >= d) sc += u;
            }
            const int excl = sc - v;
            curs[t] = excl;
            const int n = (b << BSH) + t;
            if (n < N_NODES) rowptr[n] = e0 + excl;
        }
        __syncthreads();
        for (int i = t; i < cnt; i += 256) {
            const unsigned v = ebuf[e0 + i];
            const int p = atomicAdd(&curs[v >> 17], 1);
            col[e0 + p] = (int)(v & 0x1FFFFu);
        }
    }
}

// ---------------- layer 1 GEMM: LDS-free, readlane broadcast ----------------
// wave = 8 rows x 64 cols. lane (r,q) = (l>>3, l&7) holds x[row0+r][kb*32+q*4..+3];
// broadcast via v_readlane (literal lane), FMA with per-lane W column.
#define RL(val, sl) __int_as_float(__builtin_amdgcn_readlane(__float_as_int(val), (sl)))

__global__ __launch_bounds__(256) void gemm1_kernel(
    const float* __restrict__ x, const float* __restrict__ W1,
    const float* __restrict__ a_src, const float* __restrict__ a_dst,
    __half* __restrict__ h1, float* __restrict__ as1, float* __restrict__ ad1)
{
    const int lane = threadIdx.x & 63;
    const int wave = threadIdx.x >> 6;
    const int row0 = blockIdx.x * 32 + wave * 8;   // 100000 % 32 == 0
    const int rsub = lane >> 3;
    const int koff = (lane & 7) * 4;

    const float* __restrict__ xrow = x + (size_t)(row0 + rsub) * F_IN;

    float acc[8];
#pragma unroll
    for (int r = 0; r < 8; ++r) acc[r] = 0.f;

    float4 xv = *(const float4*)(xrow + koff);     // k-block 0
    float4 cur;

    for (int kb = 0; kb < 15; ++kb) {              // k = kb*32 .. +31
        cur = xv;
        if (kb < 14) {
            xv = *(const float4*)(xrow + (kb + 1) * 32 + koff);
        } else if (koff < 20) {                    // tail block k=480..499
            xv = *(const float4*)(xrow + 480 + koff);
        }
        const float* wp = W1 + kb * 32 * F1 + lane;
#pragma unroll
        for (int q = 0; q < 8; ++q) {
            const float w0 = wp[0];
            const float w1 = wp[F1];
            const float w2 = wp[2 * F1];
            const float w3 = wp[3 * F1];
            wp += 4 * F1;
#pragma unroll
            for (int r = 0; r < 8; ++r) {
                const int sl = r * 8 + q;
                acc[r] = fmaf(RL(cur.x, sl), w0, acc[r]);
                acc[r] = fmaf(RL(cur.y, sl), w1, acc[r]);
                acc[r] = fmaf(RL(cur.z, sl), w2, acc[r]);
                acc[r] = fmaf(RL(cur.w, sl), w3, acc[r]);
            }
        }
    }
    {   // tail: k = 480..499 (5 k4-groups)
        cur = xv;
        const float* wp = W1 + 480 * F1 + lane;
#pragma unroll
        for (int q = 0; q < 5; ++q) {
            const float w0 = wp[0];
            const float w1 = wp[F1];
            const float w2 = wp[2 * F1];
            const float w3 = wp[3 * F1];
            wp += 4 * F1;
#pragma unroll
            for (int r = 0; r < 8; ++r) {
                const int sl = r * 8 + q;
                acc[r] = fmaf(RL(cur.x, sl), w0, acc[r]);
                acc[r] = fmaf(RL(cur.y, sl), w1, acc[r]);
                acc[r] = fmaf(RL(cur.z, sl), w2, acc[r]);
                acc[r] = fmaf(RL(cur.w, sl), w3, acc[r]);
            }
        }
    }

    const float asc = a_src[lane];   // flat [h*8+c] == lane
    const float adc = a_dst[lane];
#pragma unroll
    for (int r = 0; r < 8; ++r) {
        const int gr = row0 + r;
        float ps = acc[r] * asc;
        float pd = acc[r] * adc;
#pragma unroll
        for (int m = 1; m < 8; m <<= 1) {
            ps += __shfl_xor(ps, m, 8);
            pd += __shfl_xor(pd, m, 8);
        }
        h1[(size_t)gr * F1 + lane] = __float2half(acc[r]);
        if ((lane & 7) == 0) {
            as1[gr * H1 + (lane >> 3)] = ps;
            ad1[gr * H1 + (lane >> 3)] = pd;
        }
    }
}

// ---------------- layer 1 aggregation: wave per node (fp16 h1) ----------------
__global__ __launch_bounds__(256) void agg1_kernel(
    const int* __restrict__ rowptr, const int* __restrict__ col,
    const __half* __restrict__ h1, const float* __restrict__ as1,
    const float* __restrict__ ad1, const float* __restrict__ b1,
    float* __restrict__ hout)
{
    const int lane = threadIdx.x & 63;
    const int n = (blockIdx.x << 2) + (threadIdx.x >> 6);
    if (n >= N_NODES) return;
    const int h = lane >> 3;
    const int r0 = rowptr[n], r1 = rowptr[n + 1];
    const float adh = ad1[(n << 3) + h];

    float m = -1e30f, denom = 0.f, acc = 0.f;
    int j = r0;
    for (; j + 4 <= r1; j += 4) {
        const int s0 = col[j], s1 = col[j + 1], s2 = col[j + 2], s3 = col[j + 3];
        const float f0 = as1[(s0 << 3) + h], f1 = as1[(s1 << 3) + h];
        const float f2 = as1[(s2 << 3) + h], f3 = as1[(s3 << 3) + h];
        const float v0 = __half2float(h1[(s0 << 6) + lane]);
        const float v1 = __half2float(h1[(s1 << 6) + lane]);
        const float v2 = __half2float(h1[(s2 << 6) + lane]);
        const float v3 = __half2float(h1[(s3 << 6) + lane]);
        float e0 = f0 + adh; e0 = fmaxf(e0, 0.2f * e0);
        float e1 = f1 + adh; e1 = fmaxf(e1, 0.2f * e1);
        float e2 = f2 + adh; e2 = fmaxf(e2, 0.2f * e2);
        float e3 = f3 + adh; e3 = fmaxf(e3, 0.2f * e3);
        const float nm = fmaxf(fmaxf(m, fmaxf(e0, e1)), fmaxf(e2, e3));
        const float sc = __expf(m - nm);
        const float p0 = __expf(e0 - nm), p1 = __expf(e1 - nm);
        const float p2 = __expf(e2 - nm), p3 = __expf(e3 - nm);
        denom = fmaf(denom, sc, (p0 + p1) + (p2 + p3));
        acc *= sc;
        acc = fmaf(p0, v0, acc);
        acc = fmaf(p1, v1, acc);
        acc = fmaf(p2, v2, acc);
        acc = fmaf(p3, v3, acc);
        m = nm;
    }
    for (; j < r1; ++j) {
        const int s = col[j];
        float e = as1[(s << 3) + h] + adh;
        e = fmaxf(e, 0.2f * e);
        const float v = __half2float(h1[(s << 6) + lane]);
        const float nm = fmaxf(m, e);
        const float sc = __expf(m - nm);
        const float p = __expf(e - nm);
        denom = fmaf(denom, sc, p);
        acc = fmaf(p, v, acc * sc);
        m = nm;
    }
    hout[(n << 6) + lane] = acc / denom + b1[lane];
}

// ---------------- layer 2 GEMM + attention coefficients ----------------
__global__ __launch_bounds__(256) void gemm2_kernel(
    const float* __restrict__ hin, const float* __restrict__ W2,
    const float* __restrict__ a_src, const float* __restrict__ a_dst,
    float* __restrict__ h2p, float* __restrict__ as2, float* __restrict__ ad2)
{
    __shared__ float w2s[F1 * C2];
    __shared__ float as_s[C2], ad_s[C2];
    for (int i = threadIdx.x; i < F1 * C2; i += blockDim.x) w2s[i] = W2[i];
    if (threadIdx.x < C2) { as_s[threadIdx.x] = a_src[threadIdx.x]; ad_s[threadIdx.x] = a_dst[threadIdx.x]; }
    __syncthreads();

    int n = blockIdx.x * blockDim.x + threadIdx.x;
    if (n >= N_NODES) return;
    float acc[C2];
#pragma unroll
    for (int c = 0; c < C2; ++c) acc[c] = 0.f;
    const float* hp = hin + (size_t)n * F1;
    for (int k = 0; k < F1; k += 4) {
        const float4 hv = *(const float4*)(hp + k);
#pragma unroll
        for (int c = 0; c < C2; ++c) {
            acc[c] = fmaf(hv.x, w2s[(k + 0) * C2 + c], acc[c]);
            acc[c] = fmaf(hv.y, w2s[(k + 1) * C2 + c], acc[c]);
            acc[c] = fmaf(hv.z, w2s[(k + 2) * C2 + c], acc[c]);
            acc[c] = fmaf(hv.w, w2s[(k + 3) * C2 + c], acc[c]);
        }
    }
    float s = 0.f, d = 0.f;
#pragma unroll
    for (int c = 0; c < C2; ++c) {
        s = fmaf(acc[c], as_s[c], s);
        d = fmaf(acc[c], ad_s[c], d);
    }
    float4* o = (float4*)(h2p + (size_t)n * 8);
    o[0] = make_float4(acc[0], acc[1], acc[2], acc[3]);
    o[1] = make_float4(acc[4], acc[5], acc[6], 0.f);
    as2[n] = s;
    ad2[n] = d;
}

// ---------------- layer 2 aggregation + bias + log_softmax ----------------
__global__ __launch_bounds__(256) void agg2_kernel(
    const int* __restrict__ rowptr, const int* __restrict__ col,
    const float* __restrict__ h2p, const float* __restrict__ as2,
    const float* __restrict__ ad2, const float* __restrict__ b2,
    float* __restrict__ out)
{
    const int gq = (blockIdx.x * 256 + threadIdx.x) >> 2;   // node
    const int q = threadIdx.x & 3;
    if (gq >= N_NODES) return;
    const int r0 = rowptr[gq], r1 = rowptr[gq + 1];
    const float adn = ad2[gq];

    float m = -1e30f, denom = 0.f;
    float a0 = 0, a1 = 0, a2 = 0, a3 = 0, a4 = 0, a5 = 0, a6 = 0;
    for (int j = r0 + q; j < r1; j += 4) {
        const int s = col[j];
        float e = as2[s] + adn;
        e = fmaxf(e, 0.2f * e);
        const float4 va = *(const float4*)(h2p + (size_t)s * 8);
        const float4 vb = *(const float4*)(h2p + (size_t)s * 8 + 4);
        const float nm = fmaxf(m, e);
        const float sc = __expf(m - nm);
        const float ex = __expf(e - nm);
        denom = fmaf(denom, sc, ex);
        a0 = fmaf(ex, va.x, a0 * sc); a1 = fmaf(ex, va.y, a1 * sc);
        a2 = fmaf(ex, va.z, a2 * sc); a3 = fmaf(ex, va.w, a3 * sc);
        a4 = fmaf(ex, vb.x, a4 * sc); a5 = fmaf(ex, vb.y, a5 * sc);
        a6 = fmaf(ex, vb.z, a6 * sc);
        m = nm;
    }
#pragma unroll
    for (int d = 1; d < 4; d <<= 1) {
        const float om = __shfl_xor(m, d);
        const float od = __shfl_xor(denom, d);
        const float o0 = __shfl_xor(a0, d), o1 = __shfl_xor(a1, d);
        const float o2 = __shfl_xor(a2, d), o3 = __shfl_xor(a3, d);
        const float o4 = __shfl_xor(a4, d), o5 = __shfl_xor(a5, d);
        const float o6 = __shfl_xor(a6, d);
        const float nm = fmaxf(m, om);
        const float s1 = __expf(m - nm);
        const float s2 = __expf(om - nm);
        denom = denom * s1 + od * s2;
        a0 = a0 * s1 + o0 * s2; a1 = a1 * s1 + o1 * s2;
        a2 = a2 * s1 + o2 * s2; a3 = a3 * s1 + o3 * s2;
        a4 = a4 * s1 + o4 * s2; a5 = a5 * s1 + o5 * s2;
        a6 = a6 * s1 + o6 * s2;
        m = nm;
    }
    const float inv = 1.f / denom;
    float v0 = a0 * inv + b2[0], v1 = a1 * inv + b2[1];
    float v2 = a2 * inv + b2[2], v3 = a3 * inv + b2[3];
    float v4 = a4 * inv + b2[4], v5 = a5 * inv + b2[5];
    float v6 = a6 * inv + b2[6];
    float mx = fmaxf(fmaxf(fmaxf(v0, v1), fmaxf(v2, v3)), fmaxf(fmaxf(v4, v5), v6));
    const float se = __expf(v0 - mx) + __expf(v1 - mx) + __expf(v2 - mx) +
                     __expf(v3 - mx) + __expf(v4 - mx) + __expf(v5 - mx) +
                     __expf(v6 - mx);
    const float lse = __logf(se) + mx;
    const float wa = (q == 0) ? v0 : (q == 1) ? v1 : (q == 2) ? v2 : v3;
    const float wb = (q == 0) ? v4 : (q == 1) ? v5 : v6;
    out[gq * C2 + q] = wa - lse;
    if (q < 3) out[gq * C2 + q + 4] = wb - lse;
}

extern "C" void kernel_launch(void* const* d_in, const int* in_sizes, int n_in,
                              void* d_out, int out_size, void* d_ws, size_t ws_size,
                              hipStream_t stream) {
    const float* x      = (const float*)d_in[0];
    const int*   ei     = (const int*)  d_in[1];
    const float* W1     = (const float*)d_in[2];
    const float* a_src1 = (const float*)d_in[3];
    const float* a_dst1 = (const float*)d_in[4];
    const float* b1     = (const float*)d_in[5];
    const float* W2     = (const float*)d_in[6];
    const float* a_src2 = (const float*)d_in[7];
    const float* a_dst2 = (const float*)d_in[8];
    const float* b2     = (const float*)d_in[9];
    float* out = (float*)d_out;

    char* ws = (char*)d_ws;
    size_t off = 0;
    auto alloc = [&](size_t bytes) -> void* {
        void* p = ws + off;
        off += (bytes + 255) & ~(size_t)255;
        return p;
    };
    int*    rowptr  = (int*)   alloc((N_NODES + 1) * sizeof(int));
    int*    boff    = (int*)   alloc((size_t)(NB + 1) * sizeof(int));
    int*    cntmat  = (int*)   alloc((size_t)FB * NB * sizeof(int));
    int*    basemat = (int*)   alloc((size_t)FB * NB * sizeof(int));
    int*    colidx  = (int*)   alloc((size_t)ET * sizeof(int));
    __half* h1      = (__half*)alloc((size_t)N_NODES * F1 * sizeof(__half));
    float*  as1     = (float*) alloc((size_t)N_NODES * H1 * sizeof(float));
    float*  ad1     = (float*) alloc((size_t)N_NODES * H1 * sizeof(float));
    float*  hout1   = (float*) alloc((size_t)N_NODES * F1 * sizeof(float));
    float*  h2p     = (float*) alloc((size_t)N_NODES * 8 * sizeof(float));
    float*  as2     = (float*) alloc((size_t)N_NODES * sizeof(float));
    float*  ad2     = (float*) alloc((size_t)N_NODES * sizeof(float));
    // ebuf aliases hout1 (hout1 is dead until agg1, which runs after bucket_csr)
    unsigned int* ebuf = (unsigned int*)hout1;

    fill_count<<<FB, 1024, 0, stream>>>(ei, cntmat);
    scan2<<<1, 1024, 0, stream>>>(cntmat, boff, basemat, rowptr);
    fill_scatter<<<FB, 1024, 0, stream>>>(ei, basemat, ebuf);
    bucket_csr<<<NB, 256, 0, stream>>>(boff, ebuf, colidx, rowptr);
    gemm1_kernel<<<N_NODES / 32, 256, 0, stream>>>(x, W1, a_src1, a_dst1, h1, as1, ad1);
    agg1_kernel<<<(N_NODES + 3) / 4, 256, 0, stream>>>(rowptr, colidx, h1, as1, ad1, b1, hout1);
    gemm2_kernel<<<(N_NODES + 255) / 256, 256, 0, stream>>>(hout1, W2, a_src2, a_dst2, h2p, as2, ad2);
    agg2_kernel<<<(N_NODES * 4 + 255) / 256, 256, 0, stream>>>(rowptr, colidx, h2p, as2, ad2, b2, out);
}

// Round 7
// 489.156 us; speedup vs baseline: 2.0646x; 1.0492x over previous
//
#include <hip/hip_runtime.h>
#include <hip/hip_bf16.h>
#include <hip/hip_fp16.h>

#define N_NODES 100000
#define N_EDGES 3200000
#define ET (N_EDGES + N_NODES)   // edges + self loops
#define F_IN 500
#define H1 8
#define C1 8
#define F1 64                    // H1*C1
#define C2 7

#define BSH 6                    // 64 nodes per bucket
#define NB ((N_NODES + 63) / 64) // 1563
#define CAP 6144                 // LDS edge capacity per bucket (avg ~2111)
#define FB 64                    // partition blocks
#define FCHUNK ((ET + FB - 1) / FB)

typedef __attribute__((ext_vector_type(8))) short short8;
typedef __attribute__((ext_vector_type(4))) float f32x4;

__device__ __forceinline__ unsigned short f2bf(float f) {
    const unsigned u = __float_as_uint(f);
    return (unsigned short)((u + 0x7FFFu + ((u >> 16) & 1u)) >> 16);
}

// ---------------- CSR build: atomic-free 3-phase partition ----------------
__global__ __launch_bounds__(1024) void fill_count(const int* __restrict__ ei,
                                                   int* __restrict__ cntmat) {
    __shared__ int hist[NB];
    const int t = threadIdx.x, blk = blockIdx.x;
    for (int i = t; i < NB; i += 1024) hist[i] = 0;
    __syncthreads();
    const int s0 = blk * FCHUNK;
    const int s1 = min(s0 + FCHUNK, ET);
    for (int i = s0 + t; i < s1; i += 1024) {
        const int dst = (i < N_EDGES) ? ei[N_EDGES + i] : (i - N_EDGES);
        atomicAdd(&hist[dst >> BSH], 1);
    }
    __syncthreads();
    int* row = cntmat + (size_t)blk * NB;
    for (int i = t; i < NB; i += 1024) row[i] = hist[i];
}

__global__ __launch_bounds__(1024) void scan2(const int* __restrict__ cntmat,
                                              int* __restrict__ boff,
                                              int* __restrict__ basemat,
                                              int* __restrict__ rowptr) {
    __shared__ int tot[2048];
    __shared__ int wsum[16];
    const int t = threadIdx.x;
    const int lane = t & 63;
    const int w = t >> 6;
    for (int b = t; b < 2048; b += 1024) {
        int s = 0;
        if (b < NB)
            for (int j = 0; j < FB; ++j) s += cntmat[(size_t)j * NB + b];
        tot[b] = s;
    }
    __syncthreads();
    int running = 0;
    for (int t0 = 0; t0 < 2048; t0 += 1024) {
        const int v = tot[t0 + t];
        int sc = v;
#pragma unroll
        for (int d = 1; d < 64; d <<= 1) {
            int u = __shfl_up(sc, d);
            if (lane >= d) sc += u;
        }
        if (lane == 63) wsum[w] = sc;
        __syncthreads();
        if (t < 16) {
            int ws = wsum[t];
#pragma unroll
            for (int d = 1; d < 16; d <<= 1) {
                int u = __shfl_up(ws, d);
                if (t >= d) ws += u;
            }
            wsum[t] = ws;
        }
        __syncthreads();
        const int excl = running + (w ? wsum[w - 1] : 0) + sc - v;
        if (t0 + t < NB) boff[t0 + t] = excl;
        const int tt = wsum[15];
        __syncthreads();
        tot[t0 + t] = excl;
        running += tt;
    }
    if (t == 0) {
        boff[NB] = running;            // == ET
        rowptr[N_NODES] = running;
    }
    __syncthreads();
    for (int b = t; b < NB; b += 1024) {
        int run = tot[b];
        for (int j = 0; j < FB; ++j) {
            basemat[(size_t)j * NB + b] = run;
            run += cntmat[(size_t)j * NB + b];
        }
    }
}

__global__ __launch_bounds__(1024) void fill_scatter(const int* __restrict__ ei,
                                                     const int* __restrict__ basemat,
                                                     unsigned int* __restrict__ ebuf) {
    __shared__ int cur[NB];
    const int t = threadIdx.x, blk = blockIdx.x;
    const int* row = basemat + (size_t)blk * NB;
    for (int i = t; i < NB; i += 1024) cur[i] = row[i];
    __syncthreads();
    const int s0 = blk * FCHUNK;
    const int s1 = min(s0 + FCHUNK, ET);
    for (int i = s0 + t; i < s1; i += 1024) {
        int src, dst;
        if (i < N_EDGES) { src = ei[i]; dst = ei[N_EDGES + i]; }
        else             { src = dst = i - N_EDGES; }
        const int b = dst >> BSH;
        const int p = atomicAdd(&cur[b], 1);
        ebuf[p] = (unsigned)src | ((unsigned)(dst & 63) << 17);
    }
}

__global__ __launch_bounds__(256) void bucket_csr(const int* __restrict__ boff,
                                                  const unsigned int* __restrict__ ebuf,
                                                  int* __restrict__ col,
                                                  int* __restrict__ rowptr) {
    __shared__ unsigned int ebs[CAP];
    __shared__ int colb[CAP];
    __shared__ int hist[64], curs[64];
    const int b = blockIdx.x, t = threadIdx.x;
    const int e0 = boff[b], e1 = boff[b + 1];
    const int cnt = e1 - e0;
    if (t < 64) hist[t] = 0;
    __syncthreads();

    if (cnt <= CAP) {
        for (int i = t; i < cnt; i += 256) {
            const unsigned v = ebuf[e0 + i];
            ebs[i] = v;
            atomicAdd(&hist[v >> 17], 1);
        }
        __syncthreads();
        if (t < 64) {
            const int v = hist[t];
            int sc = v;
#pragma unroll
            for (int d = 1; d < 64; d <<= 1) {
                int u = __shfl_up(sc, d);
                if (t >= d) sc += u;
            }
            const int excl = sc - v;
            curs[t] = excl;
            const int n = (b << BSH) + t;
            if (n < N_NODES) rowptr[n] = e0 + excl;
        }
        __syncthreads();
        for (int i = t; i < cnt; i += 256) {
            const unsigned v = ebs[i];
            const int p = atomicAdd(&curs[v >> 17], 1);
            colb[p] = (int)(v & 0x1FFFFu);
        }
        __syncthreads();
        for (int i = t; i < cnt; i += 256) col[e0 + i] = colb[i];
    } else {
        for (int i = t; i < cnt; i += 256) atomicAdd(&hist[ebuf[e0 + i] >> 17], 1);
        __syncthreads();
        if (t < 64) {
            const int v = hist[t];
            int sc = v;
#pragma unroll
            for (int d = 1; d < 64; d <<= 1) {
                int u = __shfl_up(sc, d);
                if (t >= d) sc += u;
            }
            const int excl = sc - v;
            curs[t] = excl;
            const int n = (b << BSH) + t;
            if (n < N_NODES) rowptr[n] = e0 + excl;
        }
        __syncthreads();
        for (int i = t; i < cnt; i += 256) {
            const unsigned v = ebuf[e0 + i];
            const int p = atomicAdd(&curs[v >> 17], 1);
            col[e0 + p] = (int)(v & 0x1FFFFu);
        }
    }
}

// ---------------- W prep: split fp32 W1[500][64] -> bf16 Wt_hi/Wt_lo[64][512] ----
__global__ __launch_bounds__(256) void wprep(const float* __restrict__ W1,
                                             short* __restrict__ wt_hi,
                                             short* __restrict__ wt_lo) {
    const int idx = blockIdx.x * 256 + threadIdx.x;
    if (idx >= 64 * 512) return;
    const int n = idx >> 9, k = idx & 511;
    const float f = (k < F_IN) ? W1[k * F1 + n] : 0.f;
    const unsigned short h = f2bf(f);
    const float hf = __uint_as_float((unsigned)h << 16);
    wt_hi[idx] = (short)h;
    wt_lo[idx] = (short)f2bf(f - hf);
}

// ---------------- layer 1 GEMM: MFMA bf16x3 split ----------------
// block 256 = 4 waves; 64 rows/block; wave w -> rows w*16..+15, all 64 cols.
// K padded to 512, 16 steps of 32. A staged in LDS (bf16 hi/lo, pad 40).
__global__ __launch_bounds__(256) void gemm1_kernel(
    const float* __restrict__ x, const short* __restrict__ wt_hi,
    const short* __restrict__ wt_lo,
    const float* __restrict__ a_src, const float* __restrict__ a_dst,
    __half* __restrict__ h1, float* __restrict__ as1, float* __restrict__ ad1)
{
    __shared__ short xh[64][40];
    __shared__ short xl[64][40];
    const int t = threadIdx.x;
    const int l = t & 63;
    const int w = t >> 6;
    const int row0 = blockIdx.x * 64;
    const int srow = t >> 2;                 // staging: row 0..63
    const int sseg = (t & 3) << 3;           // staging: k-offset 0,8,16,24
    const float* __restrict__ xp0 =
        x + (size_t)min(row0 + srow, N_NODES - 1) * F_IN + sseg;

    f32x4 acc[4];
#pragma unroll
    for (int f = 0; f < 4; ++f) acc[f] = (f32x4){0.f, 0.f, 0.f, 0.f};

    const int arow = w * 16 + (l & 15);      // LDS row for A frag
    const int akoff = (l >> 4) * 8;          // k element offset within step

    for (int ks = 0; ks < 16; ++ks) {
        const int k0 = ks * 32;
        float v[8];
        if (k0 + sseg + 7 < F_IN) {
            const float4 a = *(const float4*)(xp0 + k0);
            const float4 b = *(const float4*)(xp0 + k0 + 4);
            v[0] = a.x; v[1] = a.y; v[2] = a.z; v[3] = a.w;
            v[4] = b.x; v[5] = b.y; v[6] = b.z; v[7] = b.w;
        } else {
#pragma unroll
            for (int j = 0; j < 8; ++j)
                v[j] = (k0 + sseg + j < F_IN) ? xp0[k0 + j] : 0.f;
        }
        short8 h8, l8;
#pragma unroll
        for (int j = 0; j < 8; ++j) {
            const unsigned short h = f2bf(v[j]);
            h8[j] = (short)h;
            l8[j] = (short)f2bf(v[j] - __uint_as_float((unsigned)h << 16));
        }
        __syncthreads();                     // previous step's reads done
        *(short8*)&xh[srow][sseg] = h8;
        *(short8*)&xl[srow][sseg] = l8;
        __syncthreads();

        const short8 ah = *(const short8*)&xh[arow][akoff];
        const short8 al = *(const short8*)&xl[arow][akoff];
#pragma unroll
        for (int f = 0; f < 4; ++f) {
            const int c = f * 16 + (l & 15);
            const short8 bh = *(const short8*)(wt_hi + (size_t)c * 512 + k0 + akoff);
            const short8 bl = *(const short8*)(wt_lo + (size_t)c * 512 + k0 + akoff);
            acc[f] = __builtin_amdgcn_mfma_f32_16x16x32_bf16(ah, bh, acc[f], 0, 0, 0);
            acc[f] = __builtin_amdgcn_mfma_f32_16x16x32_bf16(ah, bl, acc[f], 0, 0, 0);
            acc[f] = __builtin_amdgcn_mfma_f32_16x16x32_bf16(al, bh, acc[f], 0, 0, 0);
        }
    }

    // epilogue: D[row][col], row = row0 + w*16 + (l>>4)*4 + reg, col = f*16 + (l&15)
    const int g = l >> 4;
    const int p = (l & 15) >> 3;
    float asv[4], adv[4];
#pragma unroll
    for (int f = 0; f < 4; ++f) {
        asv[f] = a_src[f * 16 + (l & 15)];
        adv[f] = a_dst[f * 16 + (l & 15)];
    }
#pragma unroll
    for (int f = 0; f < 4; ++f) {
#pragma unroll
        for (int reg = 0; reg < 4; ++reg) {
            const int row = row0 + w * 16 + g * 4 + reg;
            const float hv = acc[f][reg];
            if (row < N_NODES)
                h1[(size_t)row * F1 + f * 16 + (l & 15)] = __float2half(hv);
            float ps = hv * asv[f];
            float pd = hv * adv[f];
            ps += __shfl_xor(ps, 1); ps += __shfl_xor(ps, 2); ps += __shfl_xor(ps, 4);
            pd += __shfl_xor(pd, 1); pd += __shfl_xor(pd, 2); pd += __shfl_xor(pd, 4);
            if ((l & 7) == 0 && row < N_NODES) {
                as1[row * H1 + f * 2 + p] = ps;
                ad1[row * H1 + f * 2 + p] = pd;
            }
        }
    }
}

// ---------------- layer 1 aggregation: wave per node (fp16 h1) ----------------
__global__ __launch_bounds__(256) void agg1_kernel(
    const int* __restrict__ rowptr, const int* __restrict__ col,
    const __half* __restrict__ h1, const float* __restrict__ as1,
    const float* __restrict__ ad1, const float* __restrict__ b1,
    float* __restrict__ hout)
{
    const int lane = threadIdx.x & 63;
    const int n = (blockIdx.x << 2) + (threadIdx.x >> 6);
    if (n >= N_NODES) return;
    const int h = lane >> 3;
    const int r0 = rowptr[n], r1 = rowptr[n + 1];
    const float adh = ad1[(n << 3) + h];

    float m = -1e30f, denom = 0.f, acc = 0.f;
    int j = r0;
    for (; j + 4 <= r1; j += 4) {
        const int s0 = col[j], s1 = col[j + 1], s2 = col[j + 2], s3 = col[j + 3];
        const float f0 = as1[(s0 << 3) + h], f1 = as1[(s1 << 3) + h];
        const float f2 = as1[(s2 << 3) + h], f3 = as1[(s3 << 3) + h];
        const float v0 = __half2float(h1[(s0 << 6) + lane]);
        const float v1 = __half2float(h1[(s1 << 6) + lane]);
        const float v2 = __half2float(h1[(s2 << 6) + lane]);
        const float v3 = __half2float(h1[(s3 << 6) + lane]);
        float e0 = f0 + adh; e0 = fmaxf(e0, 0.2f * e0);
        float e1 = f1 + adh; e1 = fmaxf(e1, 0.2f * e1);
        float e2 = f2 + adh; e2 = fmaxf(e2, 0.2f * e2);
        float e3 = f3 + adh; e3 = fmaxf(e3, 0.2f * e3);
        const float nm = fmaxf(fmaxf(m, fmaxf(e0, e1)), fmaxf(e2, e3));
        const float sc = __expf(m - nm);
        const float p0 = __expf(e0 - nm), p1 = __expf(e1 - nm);
        const float p2 = __expf(e2 - nm), p3 = __expf(e3 - nm);
        denom = fmaf(denom, sc, (p0 + p1) + (p2 + p3));
        acc *= sc;
        acc = fmaf(p0, v0, acc);
        acc = fmaf(p1, v1, acc);
        acc = fmaf(p2, v2, acc);
        acc = fmaf(p3, v3, acc);
        m = nm;
    }
    for (; j < r1; ++j) {
        const int s = col[j];
        float e = as1[(s << 3) + h] + adh;
        e = fmaxf(e, 0.2f * e);
        const float v = __half2float(h1[(s << 6) + lane]);
        const float nm = fmaxf(m, e);
        const float sc = __expf(m - nm);
        const float p = __expf(e - nm);
        denom = fmaf(denom, sc, p);
        acc = fmaf(p, v, acc * sc);
        m = nm;
    }
    hout[(n << 6) + lane] = acc / denom + b1[lane];
}

// ---------------- layer 2 GEMM + attention coefficients ----------------
__global__ __launch_bounds__(256) void gemm2_kernel(
    const float* __restrict__ hin, const float* __restrict__ W2,
    const float* __restrict__ a_src, const float* __restrict__ a_dst,
    float* __restrict__ h2p, float* __restrict__ as2, float* __restrict__ ad2)
{
    __shared__ float w2s[F1 * C2];
    __shared__ float as_s[C2], ad_s[C2];
    for (int i = threadIdx.x; i < F1 * C2; i += blockDim.x) w2s[i] = W2[i];
    if (threadIdx.x < C2) { as_s[threadIdx.x] = a_src[threadIdx.x]; ad_s[threadIdx.x] = a_dst[threadIdx.x]; }
    __syncthreads();

    int n = blockIdx.x * blockDim.x + threadIdx.x;
    if (n >= N_NODES) return;
    float acc[C2];
#pragma unroll
    for (int c = 0; c < C2; ++c) acc[c] = 0.f;
    const float* hp = hin + (size_t)n * F1;
    for (int k = 0; k < F1; k += 4) {
        const float4 hv = *(const float4*)(hp + k);
#pragma unroll
        for (int c = 0; c < C2; ++c) {
            acc[c] = fmaf(hv.x, w2s[(k + 0) * C2 + c], acc[c]);
            acc[c] = fmaf(hv.y, w2s[(k + 1) * C2 + c], acc[c]);
            acc[c] = fmaf(hv.z, w2s[(k + 2) * C2 + c], acc[c]);
            acc[c] = fmaf(hv.w, w2s[(k + 3) * C2 + c], acc[c]);
        }
    }
    float s = 0.f, d = 0.f;
#pragma unroll
    for (int c = 0; c < C2; ++c) {
        s = fmaf(acc[c], as_s[c], s);
        d = fmaf(acc[c], ad_s[c], d);
    }
    float4* o = (float4*)(h2p + (size_t)n * 8);
    o[0] = make_float4(acc[0], acc[1], acc[2], acc[3]);
    o[1] = make_float4(acc[4], acc[5], acc[6], 0.f);
    as2[n] = s;
    ad2[n] = d;
}

// ---------------- layer 2 aggregation + bias + log_softmax ----------------
__global__ __launch_bounds__(256) void agg2_kernel(
    const int* __restrict__ rowptr, const int* __restrict__ col,
    const float* __restrict__ h2p, const float* __restrict__ as2,
    const float* __restrict__ ad2, const float* __restrict__ b2,
    float* __restrict__ out)
{
    const int gq = (blockIdx.x * 256 + threadIdx.x) >> 2;   // node
    const int q = threadIdx.x & 3;
    if (gq >= N_NODES) return;
    const int r0 = rowptr[gq], r1 = rowptr[gq + 1];
    const float adn = ad2[gq];

    float m = -1e30f, denom = 0.f;
    float a0 = 0, a1 = 0, a2 = 0, a3 = 0, a4 = 0, a5 = 0, a6 = 0;
    for (int j = r0 + q; j < r1; j += 4) {
        const int s = col[j];
        float e = as2[s] + adn;
        e = fmaxf(e, 0.2f * e);
        const float4 va = *(const float4*)(h2p + (size_t)s * 8);
        const float4 vb = *(const float4*)(h2p + (size_t)s * 8 + 4);
        const float nm = fmaxf(m, e);
        const float sc = __expf(m - nm);
        const float ex = __expf(e - nm);
        denom = fmaf(denom, sc, ex);
        a0 = fmaf(ex, va.x, a0 * sc); a1 = fmaf(ex, va.y, a1 * sc);
        a2 = fmaf(ex, va.z, a2 * sc); a3 = fmaf(ex, va.w, a3 * sc);
        a4 = fmaf(ex, vb.x, a4 * sc); a5 = fmaf(ex, vb.y, a5 * sc);
        a6 = fmaf(ex, vb.z, a6 * sc);
        m = nm;
    }
#pragma unroll
    for (int d = 1; d < 4; d <<= 1) {
        const float om = __shfl_xor(m, d);
        const float od = __shfl_xor(denom, d);
        const float o0 = __shfl_xor(a0, d), o1 = __shfl_xor(a1, d);
        const float o2 = __shfl_xor(a2, d), o3 = __shfl_xor(a3, d);
        const float o4 = __shfl_xor(a4, d), o5 = __shfl_xor(a5, d);
        const float o6 = __shfl_xor(a6, d);
        const float nm = fmaxf(m, om);
        const float s1 = __expf(m - nm);
        const float s2 = __expf(om - nm);
        denom = denom * s1 + od * s2;
        a0 = a0 * s1 + o0 * s2; a1 = a1 * s1 + o1 * s2;
        a2 = a2 * s1 + o2 * s2; a3 = a3 * s1 + o3 * s2;
        a4 = a4 * s1 + o4 * s2; a5 = a5 * s1 + o5 * s2;
        a6 = a6 * s1 + o6 * s2;
        m = nm;
    }
    const float inv = 1.f / denom;
    float v0 = a0 * inv + b2[0], v1 = a1 * inv + b2[1];
    float v2 = a2 * inv + b2[2], v3 = a3 * inv + b2[3];
    float v4 = a4 * inv + b2[4], v5 = a5 * inv + b2[5];
    float v6 = a6 * inv + b2[6];
    float mx = fmaxf(fmaxf(fmaxf(v0, v1), fmaxf(v2, v3)), fmaxf(fmaxf(v4, v5), v6));
    const float se = __expf(v0 - mx) + __expf(v1 - mx) + __expf(v2 - mx) +
                     __expf(v3 - mx) + __expf(v4 - mx) + __expf(v5 - mx) +
                     __expf(v6 - mx);
    const float lse = __logf(se) + mx;
    const float wa = (q == 0) ? v0 : (q == 1) ? v1 : (q == 2) ? v2 : v3;
    const float wb = (q == 0) ? v4 : (q == 1) ? v5 : v6;
    out[gq * C2 + q] = wa - lse;
    if (q < 3) out[gq * C2 + q + 4] = wb - lse;
}

extern "C" void kernel_launch(void* const* d_in, const int* in_sizes, int n_in,
                              void* d_out, int out_size, void* d_ws, size_t ws_size,
                              hipStream_t stream) {
    const float* x      = (const float*)d_in[0];
    const int*   ei     = (const int*)  d_in[1];
    const float* W1     = (const float*)d_in[2];
    const float* a_src1 = (const float*)d_in[3];
    const float* a_dst1 = (const float*)d_in[4];
    const float* b1     = (const float*)d_in[5];
    const float* W2     = (const float*)d_in[6];
    const float* a_src2 = (const float*)d_in[7];
    const float* a_dst2 = (const float*)d_in[8];
    const float* b2     = (const float*)d_in[9];
    float* out = (float*)d_out;

    char* ws = (char*)d_ws;
    size_t off = 0;
    auto alloc = [&](size_t bytes) -> void* {
        void* p = ws + off;
        off += (bytes + 255) & ~(size_t)255;
        return p;
    };
    int*    rowptr  = (int*)   alloc((N_NODES + 1) * sizeof(int));
    int*    boff    = (int*)   alloc((size_t)(NB + 1) * sizeof(int));
    int*    cntmat  = (int*)   alloc((size_t)FB * NB * sizeof(int));
    int*    basemat = (int*)   alloc((size_t)FB * NB * sizeof(int));
    int*    colidx  = (int*)   alloc((size_t)ET * sizeof(int));
    short*  wt_hi   = (short*) alloc((size_t)64 * 512 * sizeof(short));
    short*  wt_lo   = (short*) alloc((size_t)64 * 512 * sizeof(short));
    __half* h1      = (__half*)alloc((size_t)N_NODES * F1 * sizeof(__half));
    float*  as1     = (float*) alloc((size_t)N_NODES * H1 * sizeof(float));
    float*  ad1     = (float*) alloc((size_t)N_NODES * H1 * sizeof(float));
    float*  hout1   = (float*) alloc((size_t)N_NODES * F1 * sizeof(float));
    float*  h2p     = (float*) alloc((size_t)N_NODES * 8 * sizeof(float));
    float*  as2     = (float*) alloc((size_t)N_NODES * sizeof(float));
    float*  ad2     = (float*) alloc((size_t)N_NODES * sizeof(float));
    // ebuf aliases hout1 (hout1 is dead until agg1, which runs after bucket_csr)
    unsigned int* ebuf = (unsigned int*)hout1;

    wprep<<<(64 * 512 + 255) / 256, 256, 0, stream>>>(W1, wt_hi, wt_lo);
    fill_count<<<FB, 1024, 0, stream>>>(ei, cntmat);
    scan2<<<1, 1024, 0, stream>>>(cntmat, boff, basemat, rowptr);
    fill_scatter<<<FB, 1024, 0, stream>>>(ei, basemat, ebuf);
    bucket_csr<<<NB, 256, 0, stream>>>(boff, ebuf, colidx, rowptr);
    gemm1_kernel<<<(N_NODES + 63) / 64, 256, 0, stream>>>(x, wt_hi, wt_lo, a_src1, a_dst1, h1, as1, ad1);
    agg1_kernel<<<(N_NODES + 3) / 4, 256, 0, stream>>>(rowptr, colidx, h1, as1, ad1, b1, hout1);
    gemm2_kernel<<<(N_NODES + 255) / 256, 256, 0, stream>>>(hout1, W2, a_src2, a_dst2, h2p, as2, ad2);
    agg2_kernel<<<(N_NODES * 4 + 255) / 256, 256, 0, stream>>>(rowptr, colidx, h2p, as2, ad2, b2, out);
}

// Round 8
// 488.398 us; speedup vs baseline: 2.0678x; 1.0016x over previous
//
#include <hip/hip_runtime.h>
#include <hip/hip_bf16.h>
#include <hip/hip_fp16.h>

#define N_NODES 100000
#define N_EDGES 3200000
#define ET (N_EDGES + N_NODES)   // edges + self loops
#define F_IN 500
#define H1 8
#define C1 8
#define F1 64                    // H1*C1
#define C2 7

#define BSH 6                    // 64 nodes per bucket
#define NB ((N_NODES + 63) / 64) // 1563
#define CAP 6144                 // LDS edge capacity per bucket (avg ~2111)
#define FB 64                    // partition blocks
#define FCHUNK ((ET + FB - 1) / FB)

typedef __attribute__((ext_vector_type(8))) short short8;
typedef __attribute__((ext_vector_type(4))) float f32x4;

__device__ __forceinline__ unsigned short f2bf(float f) {
    const unsigned u = __float_as_uint(f);
    return (unsigned short)((u + 0x7FFFu + ((u >> 16) & 1u)) >> 16);
}

// ---------------- CSR build: atomic-free 3-phase partition ----------------
__global__ __launch_bounds__(1024) void fill_count(const int* __restrict__ ei,
                                                   int* __restrict__ cntmat) {
    __shared__ int hist[NB];
    const int t = threadIdx.x, blk = blockIdx.x;
    for (int i = t; i < NB; i += 1024) hist[i] = 0;
    __syncthreads();
    const int s0 = blk * FCHUNK;
    const int s1 = min(s0 + FCHUNK, ET);
    for (int i = s0 + t; i < s1; i += 1024) {
        const int dst = (i < N_EDGES) ? ei[N_EDGES + i] : (i - N_EDGES);
        atomicAdd(&hist[dst >> BSH], 1);
    }
    __syncthreads();
    int* row = cntmat + (size_t)blk * NB;
    for (int i = t; i < NB; i += 1024) row[i] = hist[i];
}

__global__ __launch_bounds__(1024) void scan2(const int* __restrict__ cntmat,
                                              int* __restrict__ boff,
                                              int* __restrict__ basemat,
                                              int* __restrict__ rowptr) {
    __shared__ int tot[2048];
    __shared__ int wsum[16];
    const int t = threadIdx.x;
    const int lane = t & 63;
    const int w = t >> 6;
    for (int b = t; b < 2048; b += 1024) {
        int s = 0;
        if (b < NB)
            for (int j = 0; j < FB; ++j) s += cntmat[(size_t)j * NB + b];
        tot[b] = s;
    }
    __syncthreads();
    int running = 0;
    for (int t0 = 0; t0 < 2048; t0 += 1024) {
        const int v = tot[t0 + t];
        int sc = v;
#pragma unroll
        for (int d = 1; d < 64; d <<= 1) {
            int u = __shfl_up(sc, d);
            if (lane >= d) sc += u;
        }
        if (lane == 63) wsum[w] = sc;
        __syncthreads();
        if (t < 16) {
            int ws = wsum[t];
#pragma unroll
            for (int d = 1; d < 16; d <<= 1) {
                int u = __shfl_up(ws, d);
                if (t >= d) ws += u;
            }
            wsum[t] = ws;
        }
        __syncthreads();
        const int excl = running + (w ? wsum[w - 1] : 0) + sc - v;
        if (t0 + t < NB) boff[t0 + t] = excl;
        const int tt = wsum[15];
        __syncthreads();
        tot[t0 + t] = excl;
        running += tt;
    }
    if (t == 0) {
        boff[NB] = running;            // == ET
        rowptr[N_NODES] = running;
    }
    __syncthreads();
    for (int b = t; b < NB; b += 1024) {
        int run = tot[b];
        for (int j = 0; j < FB; ++j) {
            basemat[(size_t)j * NB + b] = run;
            run += cntmat[(size_t)j * NB + b];
        }
    }
}

__global__ __launch_bounds__(1024) void fill_scatter(const int* __restrict__ ei,
                                                     const int* __restrict__ basemat,
                                                     unsigned int* __restrict__ ebuf) {
    __shared__ int cur[NB];
    const int t = threadIdx.x, blk = blockIdx.x;
    const int* row = basemat + (size_t)blk * NB;
    for (int i = t; i < NB; i += 1024) cur[i] = row[i];
    __syncthreads();
    const int s0 = blk * FCHUNK;
    const int s1 = min(s0 + FCHUNK, ET);
    for (int i = s0 + t; i < s1; i += 1024) {
        int src, dst;
        if (i < N_EDGES) { src = ei[i]; dst = ei[N_EDGES + i]; }
        else             { src = dst = i - N_EDGES; }
        const int b = dst >> BSH;
        const int p = atomicAdd(&cur[b], 1);
        ebuf[p] = (unsigned)src | ((unsigned)(dst & 63) << 17);
    }
}

__global__ __launch_bounds__(256) void bucket_csr(const int* __restrict__ boff,
                                                  const unsigned int* __restrict__ ebuf,
                                                  int* __restrict__ col,
                                                  int* __restrict__ rowptr) {
    __shared__ unsigned int ebs[CAP];
    __shared__ int colb[CAP];
    __shared__ int hist[64], curs[64];
    const int b = blockIdx.x, t = threadIdx.x;
    const int e0 = boff[b], e1 = boff[b + 1];
    const int cnt = e1 - e0;
    if (t < 64) hist[t] = 0;
    __syncthreads();

    if (cnt <= CAP) {
        for (int i = t; i < cnt; i += 256) {
            const unsigned v = ebuf[e0 + i];
            ebs[i] = v;
            atomicAdd(&hist[v >> 17], 1);
        }
        __syncthreads();
        if (t < 64) {
            const int v = hist[t];
            int sc = v;
#pragma unroll
            for (int d = 1; d < 64; d <<= 1) {
                int u = __shfl_up(sc, d);
                if (t >= d) sc += u;
            }
            const int excl = sc - v;
            curs[t] = excl;
            const int n = (b << BSH) + t;
            if (n < N_NODES) rowptr[n] = e0 + excl;
        }
        __syncthreads();
        for (int i = t; i < cnt; i += 256) {
            const unsigned v = ebs[i];
            const int p = atomicAdd(&curs[v >> 17], 1);
            colb[p] = (int)(v & 0x1FFFFu);
        }
        __syncthreads();
        for (int i = t; i < cnt; i += 256) col[e0 + i] = colb[i];
    } else {
        for (int i = t; i < cnt; i += 256) atomicAdd(&hist[ebuf[e0 + i] >> 17], 1);
        __syncthreads();
        if (t < 64) {
            const int v = hist[t];
            int sc = v;
#pragma unroll
            for (int d = 1; d < 64; d <<= 1) {
                int u = __shfl_up(sc, d);
                if (t >= d) sc += u;
            }
            const int excl = sc - v;
            curs[t] = excl;
            const int n = (b << BSH) + t;
            if (n < N_NODES) rowptr[n] = e0 + excl;
        }
        __syncthreads();
        for (int i = t; i < cnt; i += 256) {
            const unsigned v = ebuf[e0 + i];
            const int p = atomicAdd(&curs[v >> 17], 1);
            col[e0 + p] = (int)(v & 0x1FFFFu);
        }
    }
}

// ---------------- W prep: split fp32 W1[500][64] -> bf16 Wt_hi/Wt_lo[64][512] ----
__global__ __launch_bounds__(256) void wprep(const float* __restrict__ W1,
                                             short* __restrict__ wt_hi,
                                             short* __restrict__ wt_lo) {
    const int idx = blockIdx.x * 256 + threadIdx.x;
    if (idx >= 64 * 512) return;
    const int n = idx >> 9, k = idx & 511;
    const float f = (k < F_IN) ? W1[k * F1 + n] : 0.f;
    const unsigned short h = f2bf(f);
    const float hf = __uint_as_float((unsigned)h << 16);
    wt_hi[idx] = (short)h;
    wt_lo[idx] = (short)f2bf(f - hf);
}

// ---------------- layer 1 GEMM: MFMA bf16x3, direct-reg A, no LDS/barriers ----
// wave w of block: rows row0=blk*64+w*16 .. +15. Lane l: A-frag row l&15,
// k-chunk (l>>4)*8. 1-step register prefetch hides global latency.
__global__ __launch_bounds__(256) void gemm1_kernel(
    const float* __restrict__ x, const short* __restrict__ wt_hi,
    const short* __restrict__ wt_lo,
    const float* __restrict__ a_src, const float* __restrict__ a_dst,
    __half* __restrict__ h1, float* __restrict__ as1, float* __restrict__ ad1)
{
    const int t = threadIdx.x;
    const int l = t & 63;
    const int w = t >> 6;
    const int row0 = blockIdx.x * 64 + w * 16;
    const int r = l & 15;
    const int koff = (l >> 4) * 8;
    const float* __restrict__ xp =
        x + (size_t)min(row0 + r, N_NODES - 1) * F_IN + koff;

    f32x4 acc[4];
#pragma unroll
    for (int f = 0; f < 4; ++f) acc[f] = (f32x4){0.f, 0.f, 0.f, 0.f};

    float4 va = *(const float4*)(xp);
    float4 vb = *(const float4*)(xp + 4);

    for (int ks = 0; ks < 16; ++ks) {
        const int k0 = ks * 32;
        float v[8];
        v[0] = va.x; v[1] = va.y; v[2] = va.z; v[3] = va.w;
        v[4] = vb.x; v[5] = vb.y; v[6] = vb.z; v[7] = vb.w;
        // prefetch next k-step (ks=14 -> guarded tail for k=480..511)
        if (ks < 14) {
            va = *(const float4*)(xp + (ks + 1) * 32);
            vb = *(const float4*)(xp + (ks + 1) * 32 + 4);
        } else if (ks == 14) {
            float tv[8];
#pragma unroll
            for (int j = 0; j < 8; ++j)
                tv[j] = (koff + j < 20) ? xp[480 + j] : 0.f;
            va = make_float4(tv[0], tv[1], tv[2], tv[3]);
            vb = make_float4(tv[4], tv[5], tv[6], tv[7]);
        }
        short8 ah, al;
#pragma unroll
        for (int j = 0; j < 8; ++j) {
            const unsigned short h = f2bf(v[j]);
            ah[j] = (short)h;
            al[j] = (short)f2bf(v[j] - __uint_as_float((unsigned)h << 16));
        }
#pragma unroll
        for (int f = 0; f < 4; ++f) {
            const int c = f * 16 + r;
            const short8 bh = *(const short8*)(wt_hi + (size_t)c * 512 + k0 + koff);
            const short8 bl = *(const short8*)(wt_lo + (size_t)c * 512 + k0 + koff);
            acc[f] = __builtin_amdgcn_mfma_f32_16x16x32_bf16(ah, bh, acc[f], 0, 0, 0);
            acc[f] = __builtin_amdgcn_mfma_f32_16x16x32_bf16(ah, bl, acc[f], 0, 0, 0);
            acc[f] = __builtin_amdgcn_mfma_f32_16x16x32_bf16(al, bh, acc[f], 0, 0, 0);
        }
    }

    // epilogue: D[row][col], row = row0 + (l>>4)*4 + reg, col = f*16 + (l&15)
    const int g = l >> 4;
    const int p = r >> 3;
    float asv[4], adv[4];
#pragma unroll
    for (int f = 0; f < 4; ++f) {
        asv[f] = a_src[f * 16 + r];
        adv[f] = a_dst[f * 16 + r];
    }
#pragma unroll
    for (int f = 0; f < 4; ++f) {
#pragma unroll
        for (int reg = 0; reg < 4; ++reg) {
            const int row = row0 + g * 4 + reg;
            const float hv = acc[f][reg];
            if (row < N_NODES)
                h1[(size_t)row * F1 + f * 16 + r] = __float2half(hv);
            float ps = hv * asv[f];
            float pd = hv * adv[f];
            ps += __shfl_xor(ps, 1); ps += __shfl_xor(ps, 2); ps += __shfl_xor(ps, 4);
            pd += __shfl_xor(pd, 1); pd += __shfl_xor(pd, 2); pd += __shfl_xor(pd, 4);
            if ((l & 7) == 0 && row < N_NODES) {
                as1[row * H1 + f * 2 + p] = ps;
                ad1[row * H1 + f * 2 + p] = pd;
            }
        }
    }
}

// ---------------- layer 1 aggregation: wave per node (fp16 h1) ----------------
__global__ __launch_bounds__(256) void agg1_kernel(
    const int* __restrict__ rowptr, const int* __restrict__ col,
    const __half* __restrict__ h1, const float* __restrict__ as1,
    const float* __restrict__ ad1, const float* __restrict__ b1,
    float* __restrict__ hout)
{
    const int lane = threadIdx.x & 63;
    const int n = (blockIdx.x << 2) + (threadIdx.x >> 6);
    if (n >= N_NODES) return;
    const int h = lane >> 3;
    const int r0 = rowptr[n], r1 = rowptr[n + 1];
    const float adh = ad1[(n << 3) + h];

    float m = -1e30f, denom = 0.f, acc = 0.f;
    int j = r0;
    for (; j + 4 <= r1; j += 4) {
        const int s0 = col[j], s1 = col[j + 1], s2 = col[j + 2], s3 = col[j + 3];
        const float f0 = as1[(s0 << 3) + h], f1 = as1[(s1 << 3) + h];
        const float f2 = as1[(s2 << 3) + h], f3 = as1[(s3 << 3) + h];
        const float v0 = __half2float(h1[(s0 << 6) + lane]);
        const float v1 = __half2float(h1[(s1 << 6) + lane]);
        const float v2 = __half2float(h1[(s2 << 6) + lane]);
        const float v3 = __half2float(h1[(s3 << 6) + lane]);
        float e0 = f0 + adh; e0 = fmaxf(e0, 0.2f * e0);
        float e1 = f1 + adh; e1 = fmaxf(e1, 0.2f * e1);
        float e2 = f2 + adh; e2 = fmaxf(e2, 0.2f * e2);
        float e3 = f3 + adh; e3 = fmaxf(e3, 0.2f * e3);
        const float nm = fmaxf(fmaxf(m, fmaxf(e0, e1)), fmaxf(e2, e3));
        const float sc = __expf(m - nm);
        const float p0 = __expf(e0 - nm), p1 = __expf(e1 - nm);
        const float p2 = __expf(e2 - nm), p3 = __expf(e3 - nm);
        denom = fmaf(denom, sc, (p0 + p1) + (p2 + p3));
        acc *= sc;
        acc = fmaf(p0, v0, acc);
        acc = fmaf(p1, v1, acc);
        acc = fmaf(p2, v2, acc);
        acc = fmaf(p3, v3, acc);
        m = nm;
    }
    for (; j < r1; ++j) {
        const int s = col[j];
        float e = as1[(s << 3) + h] + adh;
        e = fmaxf(e, 0.2f * e);
        const float v = __half2float(h1[(s << 6) + lane]);
        const float nm = fmaxf(m, e);
        const float sc = __expf(m - nm);
        const float p = __expf(e - nm);
        denom = fmaf(denom, sc, p);
        acc = fmaf(p, v, acc * sc);
        m = nm;
    }
    hout[(n << 6) + lane] = acc / denom + b1[lane];
}

// ---------------- layer 2 GEMM + attention coefficients ----------------
__global__ __launch_bounds__(256) void gemm2_kernel(
    const float* __restrict__ hin, const float* __restrict__ W2,
    const float* __restrict__ a_src, const float* __restrict__ a_dst,
    float* __restrict__ h2p, float* __restrict__ as2, float* __restrict__ ad2)
{
    __shared__ float w2s[F1 * C2];
    __shared__ float as_s[C2], ad_s[C2];
    for (int i = threadIdx.x; i < F1 * C2; i += blockDim.x) w2s[i] = W2[i];
    if (threadIdx.x < C2) { as_s[threadIdx.x] = a_src[threadIdx.x]; ad_s[threadIdx.x] = a_dst[threadIdx.x]; }
    __syncthreads();

    int n = blockIdx.x * blockDim.x + threadIdx.x;
    if (n >= N_NODES) return;
    float acc[C2];
#pragma unroll
    for (int c = 0; c < C2; ++c) acc[c] = 0.f;
    const float* hp = hin + (size_t)n * F1;
    for (int k = 0; k < F1; k += 4) {
        const float4 hv = *(const float4*)(hp + k);
#pragma unroll
        for (int c = 0; c < C2; ++c) {
            acc[c] = fmaf(hv.x, w2s[(k + 0) * C2 + c], acc[c]);
            acc[c] = fmaf(hv.y, w2s[(k + 1) * C2 + c], acc[c]);
            acc[c] = fmaf(hv.z, w2s[(k + 2) * C2 + c], acc[c]);
            acc[c] = fmaf(hv.w, w2s[(k + 3) * C2 + c], acc[c]);
        }
    }
    float s = 0.f, d = 0.f;
#pragma unroll
    for (int c = 0; c < C2; ++c) {
        s = fmaf(acc[c], as_s[c], s);
        d = fmaf(acc[c], ad_s[c], d);
    }
    float4* o = (float4*)(h2p + (size_t)n * 8);
    o[0] = make_float4(acc[0], acc[1], acc[2], acc[3]);
    o[1] = make_float4(acc[4], acc[5], acc[6], 0.f);
    as2[n] = s;
    ad2[n] = d;
}

// ---------------- layer 2 aggregation + bias + log_softmax ----------------
__global__ __launch_bounds__(256) void agg2_kernel(
    const int* __restrict__ rowptr, const int* __restrict__ col,
    const float* __restrict__ h2p, const float* __restrict__ as2,
    const float* __restrict__ ad2, const float* __restrict__ b2,
    float* __restrict__ out)
{
    const int gq = (blockIdx.x * 256 + threadIdx.x) >> 2;   // node
    const int q = threadIdx.x & 3;
    if (gq >= N_NODES) return;
    const int r0 = rowptr[gq], r1 = rowptr[gq + 1];
    const float adn = ad2[gq];

    float m = -1e30f, denom = 0.f;
    float a0 = 0, a1 = 0, a2 = 0, a3 = 0, a4 = 0, a5 = 0, a6 = 0;
    for (int j = r0 + q; j < r1; j += 4) {
        const int s = col[j];
        float e = as2[s] + adn;
        e = fmaxf(e, 0.2f * e);
        const float4 va = *(const float4*)(h2p + (size_t)s * 8);
        const float4 vb = *(const float4*)(h2p + (size_t)s * 8 + 4);
        const float nm = fmaxf(m, e);
        const float sc = __expf(m - nm);
        const float ex = __expf(e - nm);
        denom = fmaf(denom, sc, ex);
        a0 = fmaf(ex, va.x, a0 * sc); a1 = fmaf(ex, va.y, a1 * sc);
        a2 = fmaf(ex, va.z, a2 * sc); a3 = fmaf(ex, va.w, a3 * sc);
        a4 = fmaf(ex, vb.x, a4 * sc); a5 = fmaf(ex, vb.y, a5 * sc);
        a6 = fmaf(ex, vb.z, a6 * sc);
        m = nm;
    }
#pragma unroll
    for (int d = 1; d < 4; d <<= 1) {
        const float om = __shfl_xor(m, d);
        const float od = __shfl_xor(denom, d);
        const float o0 = __shfl_xor(a0, d), o1 = __shfl_xor(a1, d);
        const float o2 = __shfl_xor(a2, d), o3 = __shfl_xor(a3, d);
        const float o4 = __shfl_xor(a4, d), o5 = __shfl_xor(a5, d);
        const float o6 = __shfl_xor(a6, d);
        const float nm = fmaxf(m, om);
        const float s1 = __expf(m - nm);
        const float s2 = __expf(om - nm);
        denom = denom * s1 + od * s2;
        a0 = a0 * s1 + o0 * s2; a1 = a1 * s1 + o1 * s2;
        a2 = a2 * s1 + o2 * s2; a3 = a3 * s1 + o3 * s2;
        a4 = a4 * s1 + o4 * s2; a5 = a5 * s1 + o5 * s2;
        a6 = a6 * s1 + o6 * s2;
        m = nm;
    }
    const float inv = 1.f / denom;
    float v0 = a0 * inv + b2[0], v1 = a1 * inv + b2[1];
    float v2 = a2 * inv + b2[2], v3 = a3 * inv + b2[3];
    float v4 = a4 * inv + b2[4], v5 = a5 * inv + b2[5];
    float v6 = a6 * inv + b2[6];
    float mx = fmaxf(fmaxf(fmaxf(v0, v1), fmaxf(v2, v3)), fmaxf(fmaxf(v4, v5), v6));
    const float se = __expf(v0 - mx) + __expf(v1 - mx) + __expf(v2 - mx) +
                     __expf(v3 - mx) + __expf(v4 - mx) + __expf(v5 - mx) +
                     __expf(v6 - mx);
    const float lse = __logf(se) + mx;
    const float wa = (q == 0) ? v0 : (q == 1) ? v1 : (q == 2) ? v2 : v3;
    const float wb = (q == 0) ? v4 : (q == 1) ? v5 : v6;
    out[gq * C2 + q] = wa - lse;
    if (q < 3) out[gq * C2 + q + 4] = wb - lse;
}

extern "C" void kernel_launch(void* const* d_in, const int* in_sizes, int n_in,
                              void* d_out, int out_size, void* d_ws, size_t ws_size,
                              hipStream_t stream) {
    const float* x      = (const float*)d_in[0];
    const int*   ei     = (const int*)  d_in[1];
    const float* W1     = (const float*)d_in[2];
    const float* a_src1 = (const float*)d_in[3];
    const float* a_dst1 = (const float*)d_in[4];
    const float* b1     = (const float*)d_in[5];
    const float* W2     = (const float*)d_in[6];
    const float* a_src2 = (const float*)d_in[7];
    const float* a_dst2 = (const float*)d_in[8];
    const float* b2     = (const float*)d_in[9];
    float* out = (float*)d_out;

    char* ws = (char*)d_ws;
    size_t off = 0;
    auto alloc = [&](size_t bytes) -> void* {
        void* p = ws + off;
        off += (bytes + 255) & ~(size_t)255;
        return p;
    };
    int*    rowptr  = (int*)   alloc((N_NODES + 1) * sizeof(int));
    int*    boff    = (int*)   alloc((size_t)(NB + 1) * sizeof(int));
    int*    cntmat  = (int*)   alloc((size_t)FB * NB * sizeof(int));
    int*    basemat = (int*)   alloc((size_t)FB * NB * sizeof(int));
    int*    colidx  = (int*)   alloc((size_t)ET * sizeof(int));
    short*  wt_hi   = (short*) alloc((size_t)64 * 512 * sizeof(short));
    short*  wt_lo   = (short*) alloc((size_t)64 * 512 * sizeof(short));
    __half* h1      = (__half*)alloc((size_t)N_NODES * F1 * sizeof(__half));
    float*  as1     = (float*) alloc((size_t)N_NODES * H1 * sizeof(float));
    float*  ad1     = (float*) alloc((size_t)N_NODES * H1 * sizeof(float));
    float*  hout1   = (float*) alloc((size_t)N_NODES * F1 * sizeof(float));
    float*  h2p     = (float*) alloc((size_t)N_NODES * 8 * sizeof(float));
    float*  as2     = (float*) alloc((size_t)N_NODES * sizeof(float));
    float*  ad2     = (float*) alloc((size_t)N_NODES * sizeof(float));
    // ebuf aliases hout1 (hout1 is dead until agg1, which runs after bucket_csr)
    unsigned int* ebuf = (unsigned int*)hout1;

    wprep<<<(64 * 512 + 255) / 256, 256, 0, stream>>>(W1, wt_hi, wt_lo);
    fill_count<<<FB, 1024, 0, stream>>>(ei, cntmat);
    scan2<<<1, 1024, 0, stream>>>(cntmat, boff, basemat, rowptr);
    fill_scatter<<<FB, 1024, 0, stream>>>(ei, basemat, ebuf);
    bucket_csr<<<NB, 256, 0, stream>>>(boff, ebuf, colidx, rowptr);
    gemm1_kernel<<<(N_NODES + 63) / 64, 256, 0, stream>>>(x, wt_hi, wt_lo, a_src1, a_dst1, h1, as1, ad1);
    agg1_kernel<<<(N_NODES + 3) / 4, 256, 0, stream>>>(rowptr, colidx, h1, as1, ad1, b1, hout1);
    gemm2_kernel<<<(N_NODES + 255) / 256, 256, 0, stream>>>(hout1, W2, a_src2, a_dst2, h2p, as2, ad2);
    agg2_kernel<<<(N_NODES * 4 + 255) / 256, 256, 0, stream>>>(rowptr, colidx, h2p, as2, ad2, b2, out);
}

// Round 9
// 421.121 us; speedup vs baseline: 2.3982x; 1.1598x over previous
//
#include <hip/hip_runtime.h>
#include <hip/hip_bf16.h>
#include <hip/hip_fp16.h>

#define N_NODES 100000
#define N_EDGES 3200000
#define ET (N_EDGES + N_NODES)   // edges + self loops
#define F_IN 500
#define H1 8
#define C1 8
#define F1 64                    // H1*C1
#define C2 7

#define BSH 6                    // 64 nodes per bucket
#define NB ((N_NODES + 63) / 64) // 1563
#define CAP 6144                 // LDS edge capacity per bucket (avg ~2111)
#define FB 64                    // partition blocks
#define FCHUNK ((ET + FB - 1) / FB)

typedef __attribute__((ext_vector_type(8))) short short8;
typedef __attribute__((ext_vector_type(4))) float f32x4;

__device__ __forceinline__ unsigned short f2bf(float f) {
    const unsigned u = __float_as_uint(f);
    return (unsigned short)((u + 0x7FFFu + ((u >> 16) & 1u)) >> 16);
}

// ---------------- CSR build: atomic-free 3-phase partition ----------------
__global__ __launch_bounds__(1024) void fill_count(const int* __restrict__ ei,
                                                   int* __restrict__ cntmat) {
    __shared__ int hist[NB];
    const int t = threadIdx.x, blk = blockIdx.x;
    for (int i = t; i < NB; i += 1024) hist[i] = 0;
    __syncthreads();
    const int s0 = blk * FCHUNK;
    const int s1 = min(s0 + FCHUNK, ET);
    for (int i = s0 + t; i < s1; i += 1024) {
        const int dst = (i < N_EDGES) ? ei[N_EDGES + i] : (i - N_EDGES);
        atomicAdd(&hist[dst >> BSH], 1);
    }
    __syncthreads();
    int* row = cntmat + (size_t)blk * NB;
    for (int i = t; i < NB; i += 1024) row[i] = hist[i];
}

__global__ __launch_bounds__(1024) void scan2(const int* __restrict__ cntmat,
                                              int* __restrict__ boff,
                                              int* __restrict__ basemat,
                                              int* __restrict__ rowptr) {
    __shared__ int tot[2048];
    __shared__ int wsum[16];
    const int t = threadIdx.x;
    const int lane = t & 63;
    const int w = t >> 6;
    for (int b = t; b < 2048; b += 1024) {
        int s = 0;
        if (b < NB)
            for (int j = 0; j < FB; ++j) s += cntmat[(size_t)j * NB + b];
        tot[b] = s;
    }
    __syncthreads();
    int running = 0;
    for (int t0 = 0; t0 < 2048; t0 += 1024) {
        const int v = tot[t0 + t];
        int sc = v;
#pragma unroll
        for (int d = 1; d < 64; d <<= 1) {
            int u = __shfl_up(sc, d);
            if (lane >= d) sc += u;
        }
        if (lane == 63) wsum[w] = sc;
        __syncthreads();
        if (t < 16) {
            int ws = wsum[t];
#pragma unroll
            for (int d = 1; d < 16; d <<= 1) {
                int u = __shfl_up(ws, d);
                if (t >= d) ws += u;
            }
            wsum[t] = ws;
        }
        __syncthreads();
        const int excl = running + (w ? wsum[w - 1] : 0) + sc - v;
        if (t0 + t < NB) boff[t0 + t] = excl;
        const int tt = wsum[15];
        __syncthreads();
        tot[t0 + t] = excl;
        running += tt;
    }
    if (t == 0) {
        boff[NB] = running;            // == ET
        rowptr[N_NODES] = running;
    }
    __syncthreads();
    for (int b = t; b < NB; b += 1024) {
        int run = tot[b];
        for (int j = 0; j < FB; ++j) {
            basemat[(size_t)j * NB + b] = run;
            run += cntmat[(size_t)j * NB + b];
        }
    }
}

__global__ __launch_bounds__(1024) void fill_scatter(const int* __restrict__ ei,
                                                     const int* __restrict__ basemat,
                                                     unsigned int* __restrict__ ebuf) {
    __shared__ int cur[NB];
    const int t = threadIdx.x, blk = blockIdx.x;
    const int* row = basemat + (size_t)blk * NB;
    for (int i = t; i < NB; i += 1024) cur[i] = row[i];
    __syncthreads();
    const int s0 = blk * FCHUNK;
    const int s1 = min(s0 + FCHUNK, ET);
    for (int i = s0 + t; i < s1; i += 1024) {
        int src, dst;
        if (i < N_EDGES) { src = ei[i]; dst = ei[N_EDGES + i]; }
        else             { src = dst = i - N_EDGES; }
        const int b = dst >> BSH;
        const int p = atomicAdd(&cur[b], 1);
        ebuf[p] = (unsigned)src | ((unsigned)(dst & 63) << 17);
    }
}

__global__ __launch_bounds__(256) void bucket_csr(const int* __restrict__ boff,
                                                  const unsigned int* __restrict__ ebuf,
                                                  int* __restrict__ col,
                                                  int* __restrict__ rowptr) {
    __shared__ unsigned int ebs[CAP];
    __shared__ int colb[CAP];
    __shared__ int hist[64], curs[64];
    const int b = blockIdx.x, t = threadIdx.x;
    const int e0 = boff[b], e1 = boff[b + 1];
    const int cnt = e1 - e0;
    if (t < 64) hist[t] = 0;
    __syncthreads();

    if (cnt <= CAP) {
        for (int i = t; i < cnt; i += 256) {
            const unsigned v = ebuf[e0 + i];
            ebs[i] = v;
            atomicAdd(&hist[v >> 17], 1);
        }
        __syncthreads();
        if (t < 64) {
            const int v = hist[t];
            int sc = v;
#pragma unroll
            for (int d = 1; d < 64; d <<= 1) {
                int u = __shfl_up(sc, d);
                if (t >= d) sc += u;
            }
            const int excl = sc - v;
            curs[t] = excl;
            const int n = (b << BSH) + t;
            if (n < N_NODES) rowptr[n] = e0 + excl;
        }
        __syncthreads();
        for (int i = t; i < cnt; i += 256) {
            const unsigned v = ebs[i];
            const int p = atomicAdd(&curs[v >> 17], 1);
            colb[p] = (int)(v & 0x1FFFFu);
        }
        __syncthreads();
        for (int i = t; i < cnt; i += 256) col[e0 + i] = colb[i];
    } else {
        for (int i = t; i < cnt; i += 256) atomicAdd(&hist[ebuf[e0 + i] >> 17], 1);
        __syncthreads();
        if (t < 64) {
            const int v = hist[t];
            int sc = v;
#pragma unroll
            for (int d = 1; d < 64; d <<= 1) {
                int u = __shfl_up(sc, d);
                if (t >= d) sc += u;
            }
            const int excl = sc - v;
            curs[t] = excl;
            const int n = (b << BSH) + t;
            if (n < N_NODES) rowptr[n] = e0 + excl;
        }
        __syncthreads();
        for (int i = t; i < cnt; i += 256) {
            const unsigned v = ebuf[e0 + i];
            const int p = atomicAdd(&curs[v >> 17], 1);
            col[e0 + p] = (int)(v & 0x1FFFFu);
        }
    }
}

// ---------------- W prep: W1[500][64] -> bf16 fragment-packed wpk ----------------
// wpk[((ks*4 + f)*64 + l)*8 + j] = bf16(W1[ks*32 + (l>>4)*8 + j][f*16 + (l&15)])
// (zero-padded for k >= 500). A wave's B-fragment load is 1 contiguous KB.
__global__ __launch_bounds__(256) void wprep(const float* __restrict__ W1,
                                             short* __restrict__ wpk) {
    const int idx = blockIdx.x * 256 + threadIdx.x;
    if (idx >= 32768) return;
    const int j = idx & 7;
    const int l = (idx >> 3) & 63;
    const int f = (idx >> 9) & 3;
    const int ks = idx >> 11;
    const int k = ks * 32 + ((l >> 4) << 3) + j;
    const int col = f * 16 + (l & 15);
    const float fv = (k < F_IN) ? W1[k * F1 + col] : 0.f;
    wpk[idx] = (short)f2bf(fv);
}

// ---------------- layer 1 GEMM: MFMA, split-A (hi+lo) x bf16-W ----------------
// wave w: rows row0=blk*64+w*16 .. +15, cols 0..63. Lane l: A row l&15,
// k-chunk (l>>4)*8. A and W register double-buffered; no LDS, no barriers.
__global__ __launch_bounds__(256) void gemm1_kernel(
    const float* __restrict__ x, const short* __restrict__ wpk,
    const float* __restrict__ a_src, const float* __restrict__ a_dst,
    __half* __restrict__ h1, float* __restrict__ as1, float* __restrict__ ad1)
{
    const int t = threadIdx.x;
    const int l = t & 63;
    const int w = t >> 6;
    const int row0 = blockIdx.x * 64 + w * 16;
    const int r = l & 15;
    const int koff = (l >> 4) * 8;
    const float* __restrict__ xp =
        x + (size_t)min(row0 + r, N_NODES - 1) * F_IN + koff;
    const short* __restrict__ wl = wpk + (l << 3);

    f32x4 acc[4];
#pragma unroll
    for (int f = 0; f < 4; ++f) acc[f] = (f32x4){0.f, 0.f, 0.f, 0.f};

    float4 va = *(const float4*)(xp);
    float4 vb = *(const float4*)(xp + 4);
    short8 bcur[4];
#pragma unroll
    for (int f = 0; f < 4; ++f)
        bcur[f] = *(const short8*)(wl + (f << 9));

    for (int ks = 0; ks < 16; ++ks) {
        float v[8];
        v[0] = va.x; v[1] = va.y; v[2] = va.z; v[3] = va.w;
        v[4] = vb.x; v[5] = vb.y; v[6] = vb.z; v[7] = vb.w;
        // prefetch next A k-step (ks=14 -> guarded tail for k=480..511)
        if (ks < 14) {
            va = *(const float4*)(xp + (ks + 1) * 32);
            vb = *(const float4*)(xp + (ks + 1) * 32 + 4);
        } else if (ks == 14) {
            float tv[8];
#pragma unroll
            for (int j = 0; j < 8; ++j)
                tv[j] = (koff + j < 20) ? xp[480 + j] : 0.f;
            va = make_float4(tv[0], tv[1], tv[2], tv[3]);
            vb = make_float4(tv[4], tv[5], tv[6], tv[7]);
        }
        // prefetch next W fragments
        short8 bnext[4];
        if (ks < 15) {
#pragma unroll
            for (int f = 0; f < 4; ++f)
                bnext[f] = *(const short8*)(wl + (((ks + 1) * 4 + f) << 9));
        }
        short8 ah, al;
#pragma unroll
        for (int j = 0; j < 8; ++j) {
            const unsigned short h = f2bf(v[j]);
            ah[j] = (short)h;
            al[j] = (short)f2bf(v[j] - __uint_as_float((unsigned)h << 16));
        }
#pragma unroll
        for (int f = 0; f < 4; ++f) {
            acc[f] = __builtin_amdgcn_mfma_f32_16x16x32_bf16(ah, bcur[f], acc[f], 0, 0, 0);
            acc[f] = __builtin_amdgcn_mfma_f32_16x16x32_bf16(al, bcur[f], acc[f], 0, 0, 0);
        }
        if (ks < 15) {
#pragma unroll
            for (int f = 0; f < 4; ++f) bcur[f] = bnext[f];
        }
    }

    // epilogue: D[row][col], row = row0 + (l>>4)*4 + reg, col = f*16 + (l&15)
    const int g = l >> 4;
    const int p = r >> 3;
    float asv[4], adv[4];
#pragma unroll
    for (int f = 0; f < 4; ++f) {
        asv[f] = a_src[f * 16 + r];
        adv[f] = a_dst[f * 16 + r];
    }
#pragma unroll
    for (int f = 0; f < 4; ++f) {
#pragma unroll
        for (int reg = 0; reg < 4; ++reg) {
            const int row = row0 + g * 4 + reg;
            const float hv = acc[f][reg];
            if (row < N_NODES)
                h1[(size_t)row * F1 + f * 16 + r] = __float2half(hv);
            float ps = hv * asv[f];
            float pd = hv * adv[f];
            ps += __shfl_xor(ps, 1); ps += __shfl_xor(ps, 2); ps += __shfl_xor(ps, 4);
            pd += __shfl_xor(pd, 1); pd += __shfl_xor(pd, 2); pd += __shfl_xor(pd, 4);
            if ((l & 7) == 0 && row < N_NODES) {
                as1[row * H1 + f * 2 + p] = ps;
                ad1[row * H1 + f * 2 + p] = pd;
            }
        }
    }
}

// ---------------- layer 1 aggregation: wave per node (fp16 h1) ----------------
__global__ __launch_bounds__(256) void agg1_kernel(
    const int* __restrict__ rowptr, const int* __restrict__ col,
    const __half* __restrict__ h1, const float* __restrict__ as1,
    const float* __restrict__ ad1, const float* __restrict__ b1,
    float* __restrict__ hout)
{
    const int lane = threadIdx.x & 63;
    const int n = (blockIdx.x << 2) + (threadIdx.x >> 6);
    if (n >= N_NODES) return;
    const int h = lane >> 3;
    const int r0 = rowptr[n], r1 = rowptr[n + 1];
    const float adh = ad1[(n << 3) + h];

    float m = -1e30f, denom = 0.f, acc = 0.f;
    int j = r0;
    for (; j + 4 <= r1; j += 4) {
        const int s0 = col[j], s1 = col[j + 1], s2 = col[j + 2], s3 = col[j + 3];
        const float f0 = as1[(s0 << 3) + h], f1 = as1[(s1 << 3) + h];
        const float f2 = as1[(s2 << 3) + h], f3 = as1[(s3 << 3) + h];
        const float v0 = __half2float(h1[(s0 << 6) + lane]);
        const float v1 = __half2float(h1[(s1 << 6) + lane]);
        const float v2 = __half2float(h1[(s2 << 6) + lane]);
        const float v3 = __half2float(h1[(s3 << 6) + lane]);
        float e0 = f0 + adh; e0 = fmaxf(e0, 0.2f * e0);
        float e1 = f1 + adh; e1 = fmaxf(e1, 0.2f * e1);
        float e2 = f2 + adh; e2 = fmaxf(e2, 0.2f * e2);
        float e3 = f3 + adh; e3 = fmaxf(e3, 0.2f * e3);
        const float nm = fmaxf(fmaxf(m, fmaxf(e0, e1)), fmaxf(e2, e3));
        const float sc = __expf(m - nm);
        const float p0 = __expf(e0 - nm), p1 = __expf(e1 - nm);
        const float p2 = __expf(e2 - nm), p3 = __expf(e3 - nm);
        denom = fmaf(denom, sc, (p0 + p1) + (p2 + p3));
        acc *= sc;
        acc = fmaf(p0, v0, acc);
        acc = fmaf(p1, v1, acc);
        acc = fmaf(p2, v2, acc);
        acc = fmaf(p3, v3, acc);
        m = nm;
    }
    for (; j < r1; ++j) {
        const int s = col[j];
        float e = as1[(s << 3) + h] + adh;
        e = fmaxf(e, 0.2f * e);
        const float v = __half2float(h1[(s << 6) + lane]);
        const float nm = fmaxf(m, e);
        const float sc = __expf(m - nm);
        const float p = __expf(e - nm);
        denom = fmaf(denom, sc, p);
        acc = fmaf(p, v, acc * sc);
        m = nm;
    }
    hout[(n << 6) + lane] = acc / denom + b1[lane];
}

// ---------------- layer 2 GEMM + attention coefficients ----------------
__global__ __launch_bounds__(256) void gemm2_kernel(
    const float* __restrict__ hin, const float* __restrict__ W2,
    const float* __restrict__ a_src, const float* __restrict__ a_dst,
    float* __restrict__ h2p, float* __restrict__ as2, float* __restrict__ ad2)
{
    __shared__ float w2s[F1 * C2];
    __shared__ float as_s[C2], ad_s[C2];
    for (int i = threadIdx.x; i < F1 * C2; i += blockDim.x) w2s[i] = W2[i];
    if (threadIdx.x < C2) { as_s[threadIdx.x] = a_src[threadIdx.x]; ad_s[threadIdx.x] = a_dst[threadIdx.x]; }
    __syncthreads();

    int n = blockIdx.x * blockDim.x + threadIdx.x;
    if (n >= N_NODES) return;
    float acc[C2];
#pragma unroll
    for (int c = 0; c < C2; ++c) acc[c] = 0.f;
    const float* hp = hin + (size_t)n * F1;
    for (int k = 0; k < F1; k += 4) {
        const float4 hv = *(const float4*)(hp + k);
#pragma unroll
        for (int c = 0; c < C2; ++c) {
            acc[c] = fmaf(hv.x, w2s[(k + 0) * C2 + c], acc[c]);
            acc[c] = fmaf(hv.y, w2s[(k + 1) * C2 + c], acc[c]);
            acc[c] = fmaf(hv.z, w2s[(k + 2) * C2 + c], acc[c]);
            acc[c] = fmaf(hv.w, w2s[(k + 3) * C2 + c], acc[c]);
        }
    }
    float s = 0.f, d = 0.f;
#pragma unroll
    for (int c = 0; c < C2; ++c) {
        s = fmaf(acc[c], as_s[c], s);
        d = fmaf(acc[c], ad_s[c], d);
    }
    float4* o = (float4*)(h2p + (size_t)n * 8);
    o[0] = make_float4(acc[0], acc[1], acc[2], acc[3]);
    o[1] = make_float4(acc[4], acc[5], acc[6], 0.f);
    as2[n] = s;
    ad2[n] = d;
}

// ---------------- layer 2 aggregation + bias + log_softmax ----------------
__global__ __launch_bounds__(256) void agg2_kernel(
    const int* __restrict__ rowptr, const int* __restrict__ col,
    const float* __restrict__ h2p, const float* __restrict__ as2,
    const float* __restrict__ ad2, const float* __restrict__ b2,
    float* __restrict__ out)
{
    const int gq = (blockIdx.x * 256 + threadIdx.x) >> 2;   // node
    const int q = threadIdx.x & 3;
    if (gq >= N_NODES) return;
    const int r0 = rowptr[gq], r1 = rowptr[gq + 1];
    const float adn = ad2[gq];

    float m = -1e30f, denom = 0.f;
    float a0 = 0, a1 = 0, a2 = 0, a3 = 0, a4 = 0, a5 = 0, a6 = 0;
    for (int j = r0 + q; j < r1; j += 4) {
        const int s = col[j];
        float e = as2[s] + adn;
        e = fmaxf(e, 0.2f * e);
        const float4 va = *(const float4*)(h2p + (size_t)s * 8);
        const float4 vb = *(const float4*)(h2p + (size_t)s * 8 + 4);
        const float nm = fmaxf(m, e);
        const float sc = __expf(m - nm);
        const float ex = __expf(e - nm);
        denom = fmaf(denom, sc, ex);
        a0 = fmaf(ex, va.x, a0 * sc); a1 = fmaf(ex, va.y, a1 * sc);
        a2 = fmaf(ex, va.z, a2 * sc); a3 = fmaf(ex, va.w, a3 * sc);
        a4 = fmaf(ex, vb.x, a4 * sc); a5 = fmaf(ex, vb.y, a5 * sc);
        a6 = fmaf(ex, vb.z, a6 * sc);
        m = nm;
    }
#pragma unroll
    for (int d = 1; d < 4; d <<= 1) {
        const float om = __shfl_xor(m, d);
        const float od = __shfl_xor(denom, d);
        const float o0 = __shfl_xor(a0, d), o1 = __shfl_xor(a1, d);
        const float o2 = __shfl_xor(a2, d), o3 = __shfl_xor(a3, d);
        const float o4 = __shfl_xor(a4, d), o5 = __shfl_xor(a5, d);
        const float o6 = __shfl_xor(a6, d);
        const float nm = fmaxf(m, om);
        const float s1 = __expf(m - nm);
        const float s2 = __expf(om - nm);
        denom = denom * s1 + od * s2;
        a0 = a0 * s1 + o0 * s2; a1 = a1 * s1 + o1 * s2;
        a2 = a2 * s1 + o2 * s2; a3 = a3 * s1 + o3 * s2;
        a4 = a4 * s1 + o4 * s2; a5 = a5 * s1 + o5 * s2;
        a6 = a6 * s1 + o6 * s2;
        m = nm;
    }
    const float inv = 1.f / denom;
    float v0 = a0 * inv + b2[0], v1 = a1 * inv + b2[1];
    float v2 = a2 * inv + b2[2], v3 = a3 * inv + b2[3];
    float v4 = a4 * inv + b2[4], v5 = a5 * inv + b2[5];
    float v6 = a6 * inv + b2[6];
    float mx = fmaxf(fmaxf(fmaxf(v0, v1), fmaxf(v2, v3)), fmaxf(fmaxf(v4, v5), v6));
    const float se = __expf(v0 - mx) + __expf(v1 - mx) + __expf(v2 - mx) +
                     __expf(v3 - mx) + __expf(v4 - mx) + __expf(v5 - mx) +
                     __expf(v6 - mx);
    const float lse = __logf(se) + mx;
    const float wa = (q == 0) ? v0 : (q == 1) ? v1 : (q == 2) ? v2 : v3;
    const float wb = (q == 0) ? v4 : (q == 1) ? v5 : v6;
    out[gq * C2 + q] = wa - lse;
    if (q < 3) out[gq * C2 + q + 4] = wb - lse;
}

extern "C" void kernel_launch(void* const* d_in, const int* in_sizes, int n_in,
                              void* d_out, int out_size, void* d_ws, size_t ws_size,
                              hipStream_t stream) {
    const float* x      = (const float*)d_in[0];
    const int*   ei     = (const int*)  d_in[1];
    const float* W1     = (const float*)d_in[2];
    const float* a_src1 = (const float*)d_in[3];
    const float* a_dst1 = (const float*)d_in[4];
    const float* b1     = (const float*)d_in[5];
    const float* W2     = (const float*)d_in[6];
    const float* a_src2 = (const float*)d_in[7];
    const float* a_dst2 = (const float*)d_in[8];
    const float* b2     = (const float*)d_in[9];
    float* out = (float*)d_out;

    char* ws = (char*)d_ws;
    size_t off = 0;
    auto alloc = [&](size_t bytes) -> void* {
        void* p = ws + off;
        off += (bytes + 255) & ~(size_t)255;
        return p;
    };
    int*    rowptr  = (int*)   alloc((N_NODES + 1) * sizeof(int));
    int*    boff    = (int*)   alloc((size_t)(NB + 1) * sizeof(int));
    int*    cntmat  = (int*)   alloc((size_t)FB * NB * sizeof(int));
    int*    basemat = (int*)   alloc((size_t)FB * NB * sizeof(int));
    int*    colidx  = (int*)   alloc((size_t)ET * sizeof(int));
    short*  wpk     = (short*) alloc((size_t)32768 * sizeof(short));
    __half* h1      = (__half*)alloc((size_t)N_NODES * F1 * sizeof(__half));
    float*  as1     = (float*) alloc((size_t)N_NODES * H1 * sizeof(float));
    float*  ad1     = (float*) alloc((size_t)N_NODES * H1 * sizeof(float));
    float*  hout1   = (float*) alloc((size_t)N_NODES * F1 * sizeof(float));
    float*  h2p     = (float*) alloc((size_t)N_NODES * 8 * sizeof(float));
    float*  as2     = (float*) alloc((size_t)N_NODES * sizeof(float));
    float*  ad2     = (float*) alloc((size_t)N_NODES * sizeof(float));
    // ebuf aliases hout1 (hout1 is dead until agg1, which runs after bucket_csr)
    unsigned int* ebuf = (unsigned int*)hout1;

    wprep<<<128, 256, 0, stream>>>(W1, wpk);
    fill_count<<<FB, 1024, 0, stream>>>(ei, cntmat);
    scan2<<<1, 1024, 0, stream>>>(cntmat, boff, basemat, rowptr);
    fill_scatter<<<FB, 1024, 0, stream>>>(ei, basemat, ebuf);
    bucket_csr<<<NB, 256, 0, stream>>>(boff, ebuf, colidx, rowptr);
    gemm1_kernel<<<(N_NODES + 63) / 64, 256, 0, stream>>>(x, wpk, a_src1, a_dst1, h1, as1, ad1);
    agg1_kernel<<<(N_NODES + 3) / 4, 256, 0, stream>>>(rowptr, colidx, h1, as1, ad1, b1, hout1);
    gemm2_kernel<<<(N_NODES + 255) / 256, 256, 0, stream>>>(hout1, W2, a_src2, a_dst2, h2p, as2, ad2);
    agg2_kernel<<<(N_NODES * 4 + 255) / 256, 256, 0, stream>>>(rowptr, colidx, h2p, as2, ad2, b2, out);
}

// Round 10
// 414.696 us; speedup vs baseline: 2.4353x; 1.0155x over previous
//
#include <hip/hip_runtime.h>
#include <hip/hip_bf16.h>
#include <hip/hip_fp16.h>

#define N_NODES 100000
#define N_EDGES 3200000
#define ET (N_EDGES + N_NODES)   // edges + self loops
#define F_IN 500
#define H1 8
#define C1 8
#define F1 64                    // H1*C1
#define C2 7

#define BSH 6                    // 64 nodes per bucket
#define NB ((N_NODES + 63) / 64) // 1563
#define CAP 6144                 // LDS edge capacity per bucket (avg ~2111)
#define FB 64                    // partition blocks
#define FCHUNK ((ET + FB - 1) / FB)

typedef __attribute__((ext_vector_type(8))) short short8;
typedef __attribute__((ext_vector_type(4))) float f32x4;

__device__ __forceinline__ unsigned short f2bf(float f) {
    const unsigned u = __float_as_uint(f);
    return (unsigned short)((u + 0x7FFFu + ((u >> 16) & 1u)) >> 16);
}

// ---------------- CSR build: atomic-free 3-phase partition ----------------
__global__ __launch_bounds__(1024) void fill_count(const int* __restrict__ ei,
                                                   int* __restrict__ cntmat) {
    __shared__ int hist[NB];
    const int t = threadIdx.x, blk = blockIdx.x;
    for (int i = t; i < NB; i += 1024) hist[i] = 0;
    __syncthreads();
    const int s0 = blk * FCHUNK;
    const int s1 = min(s0 + FCHUNK, ET);
    for (int i = s0 + t; i < s1; i += 1024) {
        const int dst = (i < N_EDGES) ? ei[N_EDGES + i] : (i - N_EDGES);
        atomicAdd(&hist[dst >> BSH], 1);
    }
    __syncthreads();
    int* row = cntmat + (size_t)blk * NB;
    for (int i = t; i < NB; i += 1024) row[i] = hist[i];
}

__global__ __launch_bounds__(1024) void scan2(const int* __restrict__ cntmat,
                                              int* __restrict__ boff,
                                              int* __restrict__ basemat,
                                              int* __restrict__ rowptr) {
    __shared__ int tot[2048];
    __shared__ int wsum[16];
    const int t = threadIdx.x;
    const int lane = t & 63;
    const int w = t >> 6;
    for (int b = t; b < 2048; b += 1024) {
        int s = 0;
        if (b < NB)
            for (int j = 0; j < FB; ++j) s += cntmat[(size_t)j * NB + b];
        tot[b] = s;
    }
    __syncthreads();
    int running = 0;
    for (int t0 = 0; t0 < 2048; t0 += 1024) {
        const int v = tot[t0 + t];
        int sc = v;
#pragma unroll
        for (int d = 1; d < 64; d <<= 1) {
            int u = __shfl_up(sc, d);
            if (lane >= d) sc += u;
        }
        if (lane == 63) wsum[w] = sc;
        __syncthreads();
        if (t < 16) {
            int ws = wsum[t];
#pragma unroll
            for (int d = 1; d < 16; d <<= 1) {
                int u = __shfl_up(ws, d);
                if (t >= d) ws += u;
            }
            wsum[t] = ws;
        }
        __syncthreads();
        const int excl = running + (w ? wsum[w - 1] : 0) + sc - v;
        if (t0 + t < NB) boff[t0 + t] = excl;
        const int tt = wsum[15];
        __syncthreads();
        tot[t0 + t] = excl;
        running += tt;
    }
    if (t == 0) {
        boff[NB] = running;            // == ET
        rowptr[N_NODES] = running;
    }
    __syncthreads();
    for (int b = t; b < NB; b += 1024) {
        int run = tot[b];
        for (int j = 0; j < FB; ++j) {
            basemat[(size_t)j * NB + b] = run;
            run += cntmat[(size_t)j * NB + b];
        }
    }
}

__global__ __launch_bounds__(1024) void fill_scatter(const int* __restrict__ ei,
                                                     const int* __restrict__ basemat,
                                                     unsigned int* __restrict__ ebuf) {
    __shared__ int cur[NB];
    const int t = threadIdx.x, blk = blockIdx.x;
    const int* row = basemat + (size_t)blk * NB;
    for (int i = t; i < NB; i += 1024) cur[i] = row[i];
    __syncthreads();
    const int s0 = blk * FCHUNK;
    const int s1 = min(s0 + FCHUNK, ET);
    for (int i = s0 + t; i < s1; i += 1024) {
        int src, dst;
        if (i < N_EDGES) { src = ei[i]; dst = ei[N_EDGES + i]; }
        else             { src = dst = i - N_EDGES; }
        const int b = dst >> BSH;
        const int p = atomicAdd(&cur[b], 1);
        ebuf[p] = (unsigned)src | ((unsigned)(dst & 63) << 17);
    }
}

__global__ __launch_bounds__(256) void bucket_csr(const int* __restrict__ boff,
                                                  const unsigned int* __restrict__ ebuf,
                                                  int* __restrict__ col,
                                                  int* __restrict__ rowptr) {
    __shared__ unsigned int ebs[CAP];
    __shared__ int colb[CAP];
    __shared__ int hist[64], curs[64];
    const int b = blockIdx.x, t = threadIdx.x;
    const int e0 = boff[b], e1 = boff[b + 1];
    const int cnt = e1 - e0;
    if (t < 64) hist[t] = 0;
    __syncthreads();

    if (cnt <= CAP) {
        for (int i = t; i < cnt; i += 256) {
            const unsigned v = ebuf[e0 + i];
            ebs[i] = v;
            atomicAdd(&hist[v >> 17], 1);
        }
        __syncthreads();
        if (t < 64) {
            const int v = hist[t];
            int sc = v;
#pragma unroll
            for (int d = 1; d < 64; d <<= 1) {
                int u = __shfl_up(sc, d);
                if (t >= d) sc += u;
            }
            const int excl = sc - v;
            curs[t] = excl;
            const int n = (b << BSH) + t;
            if (n < N_NODES) rowptr[n] = e0 + excl;
        }
        __syncthreads();
        for (int i = t; i < cnt; i += 256) {
            const unsigned v = ebs[i];
            const int p = atomicAdd(&curs[v >> 17], 1);
            colb[p] = (int)(v & 0x1FFFFu);
        }
        __syncthreads();
        for (int i = t; i < cnt; i += 256) col[e0 + i] = colb[i];
    } else {
        for (int i = t; i < cnt; i += 256) atomicAdd(&hist[ebuf[e0 + i] >> 17], 1);
        __syncthreads();
        if (t < 64) {
            const int v = hist[t];
            int sc = v;
#pragma unroll
            for (int d = 1; d < 64; d <<= 1) {
                int u = __shfl_up(sc, d);
                if (t >= d) sc += u;
            }
            const int excl = sc - v;
            curs[t] = excl;
            const int n = (b << BSH) + t;
            if (n < N_NODES) rowptr[n] = e0 + excl;
        }
        __syncthreads();
        for (int i = t; i < cnt; i += 256) {
            const unsigned v = ebuf[e0 + i];
            const int p = atomicAdd(&curs[v >> 17], 1);
            col[e0 + p] = (int)(v & 0x1FFFFu);
        }
    }
}

// ---------------- W prep: W1[500][64] -> bf16 fragment-packed wpk ----------------
__global__ __launch_bounds__(256) void wprep(const float* __restrict__ W1,
                                             short* __restrict__ wpk) {
    const int idx = blockIdx.x * 256 + threadIdx.x;
    if (idx >= 32768) return;
    const int j = idx & 7;
    const int l = (idx >> 3) & 63;
    const int f = (idx >> 9) & 3;
    const int ks = idx >> 11;
    const int k = ks * 32 + ((l >> 4) << 3) + j;
    const int col = f * 16 + (l & 15);
    const float fv = (k < F_IN) ? W1[k * F1 + col] : 0.f;
    wpk[idx] = (short)f2bf(fv);
}

// ---------------- layer 1 GEMM: MFMA, split-A (hi+lo) x bf16-W ----------------
__global__ __launch_bounds__(256) void gemm1_kernel(
    const float* __restrict__ x, const short* __restrict__ wpk,
    const float* __restrict__ a_src, const float* __restrict__ a_dst,
    __half* __restrict__ h1, float* __restrict__ as1, float* __restrict__ ad1)
{
    const int t = threadIdx.x;
    const int l = t & 63;
    const int w = t >> 6;
    const int row0 = blockIdx.x * 64 + w * 16;
    const int r = l & 15;
    const int koff = (l >> 4) * 8;
    const float* __restrict__ xp =
        x + (size_t)min(row0 + r, N_NODES - 1) * F_IN + koff;
    const short* __restrict__ wl = wpk + (l << 3);

    f32x4 acc[4];
#pragma unroll
    for (int f = 0; f < 4; ++f) acc[f] = (f32x4){0.f, 0.f, 0.f, 0.f};

    float4 va = *(const float4*)(xp);
    float4 vb = *(const float4*)(xp + 4);
    short8 bcur[4];
#pragma unroll
    for (int f = 0; f < 4; ++f)
        bcur[f] = *(const short8*)(wl + (f << 9));

    for (int ks = 0; ks < 16; ++ks) {
        float v[8];
        v[0] = va.x; v[1] = va.y; v[2] = va.z; v[3] = va.w;
        v[4] = vb.x; v[5] = vb.y; v[6] = vb.z; v[7] = vb.w;
        if (ks < 14) {
            va = *(const float4*)(xp + (ks + 1) * 32);
            vb = *(const float4*)(xp + (ks + 1) * 32 + 4);
        } else if (ks == 14) {
            float tv[8];
#pragma unroll
            for (int j = 0; j < 8; ++j)
                tv[j] = (koff + j < 20) ? xp[480 + j] : 0.f;
            va = make_float4(tv[0], tv[1], tv[2], tv[3]);
            vb = make_float4(tv[4], tv[5], tv[6], tv[7]);
        }
        short8 bnext[4];
        if (ks < 15) {
#pragma unroll
            for (int f = 0; f < 4; ++f)
                bnext[f] = *(const short8*)(wl + (((ks + 1) * 4 + f) << 9));
        }
        short8 ah, al;
#pragma unroll
        for (int j = 0; j < 8; ++j) {
            const unsigned short h = f2bf(v[j]);
            ah[j] = (short)h;
            al[j] = (short)f2bf(v[j] - __uint_as_float((unsigned)h << 16));
        }
#pragma unroll
        for (int f = 0; f < 4; ++f) {
            acc[f] = __builtin_amdgcn_mfma_f32_16x16x32_bf16(ah, bcur[f], acc[f], 0, 0, 0);
            acc[f] = __builtin_amdgcn_mfma_f32_16x16x32_bf16(al, bcur[f], acc[f], 0, 0, 0);
        }
        if (ks < 15) {
#pragma unroll
            for (int f = 0; f < 4; ++f) bcur[f] = bnext[f];
        }
    }

    // epilogue: D[row][col], row = row0 + (l>>4)*4 + reg, col = f*16 + (l&15)
    const int g = l >> 4;
    const int p = r >> 3;
    float asv[4], adv[4];
#pragma unroll
    for (int f = 0; f < 4; ++f) {
        asv[f] = a_src[f * 16 + r];
        adv[f] = a_dst[f * 16 + r];
    }
#pragma unroll
    for (int f = 0; f < 4; ++f) {
#pragma unroll
        for (int reg = 0; reg < 4; ++reg) {
            const int row = row0 + g * 4 + reg;
            const float hv = acc[f][reg];
            if (row < N_NODES)
                h1[(size_t)row * F1 + f * 16 + r] = __float2half(hv);
            float ps = hv * asv[f];
            float pd = hv * adv[f];
            ps += __shfl_xor(ps, 1); ps += __shfl_xor(ps, 2); ps += __shfl_xor(ps, 4);
            pd += __shfl_xor(pd, 1); pd += __shfl_xor(pd, 2); pd += __shfl_xor(pd, 4);
            if ((l & 7) == 0 && row < N_NODES) {
                as1[row * H1 + f * 2 + p] = ps;
                ad1[row * H1 + f * 2 + p] = pd;
            }
        }
    }
}

// ---------------- layer 1 aggregation: wave per node, no-max softmax ----------
// e = leaky(as+ad) ~ N(0,2), |e| < ~10 over 3.3M samples; exp(e) cannot
// overflow fp32 (needs e>88). exp(e)/sum == reference's exp(e-m)/sum exactly
// up to ~1ulp of v_exp. Removes the serial rescale chain: 7 VALU/edge.
__global__ __launch_bounds__(256) void agg1_kernel(
    const int* __restrict__ rowptr, const int* __restrict__ col,
    const __half* __restrict__ h1, const float* __restrict__ as1,
    const float* __restrict__ ad1, const float* __restrict__ b1,
    float* __restrict__ hout)
{
    const int lane = threadIdx.x & 63;
    const int n = (blockIdx.x << 2) + (threadIdx.x >> 6);
    if (n >= N_NODES) return;
    const int h = lane >> 3;
    const int r0 = rowptr[n], r1 = rowptr[n + 1];
    const float adh = ad1[(n << 3) + h];

    float denom = 0.f, acc = 0.f;
    int j = r0;
    for (; j + 4 <= r1; j += 4) {
        const int s0 = col[j], s1 = col[j + 1], s2 = col[j + 2], s3 = col[j + 3];
        const float f0 = as1[(s0 << 3) + h], f1 = as1[(s1 << 3) + h];
        const float f2 = as1[(s2 << 3) + h], f3 = as1[(s3 << 3) + h];
        const float v0 = __half2float(h1[(s0 << 6) + lane]);
        const float v1 = __half2float(h1[(s1 << 6) + lane]);
        const float v2 = __half2float(h1[(s2 << 6) + lane]);
        const float v3 = __half2float(h1[(s3 << 6) + lane]);
        float e0 = f0 + adh; e0 = fmaxf(e0, 0.2f * e0);
        float e1 = f1 + adh; e1 = fmaxf(e1, 0.2f * e1);
        float e2 = f2 + adh; e2 = fmaxf(e2, 0.2f * e2);
        float e3 = f3 + adh; e3 = fmaxf(e3, 0.2f * e3);
        const float p0 = __expf(e0), p1 = __expf(e1);
        const float p2 = __expf(e2), p3 = __expf(e3);
        denom += (p0 + p1) + (p2 + p3);
        acc = fmaf(p0, v0, acc);
        acc = fmaf(p1, v1, acc);
        acc = fmaf(p2, v2, acc);
        acc = fmaf(p3, v3, acc);
    }
    for (; j < r1; ++j) {
        const int s = col[j];
        float e = as1[(s << 3) + h] + adh;
        e = fmaxf(e, 0.2f * e);
        const float p = __expf(e);
        const float v = __half2float(h1[(s << 6) + lane]);
        denom += p;
        acc = fmaf(p, v, acc);
    }
    hout[(n << 6) + lane] = acc / denom + b1[lane];
}

// ---------------- layer 2 GEMM + attention coefficients ----------------
__global__ __launch_bounds__(256) void gemm2_kernel(
    const float* __restrict__ hin, const float* __restrict__ W2,
    const float* __restrict__ a_src, const float* __restrict__ a_dst,
    float* __restrict__ h2p, float* __restrict__ as2, float* __restrict__ ad2)
{
    __shared__ float w2s[F1 * C2];
    __shared__ float as_s[C2], ad_s[C2];
    for (int i = threadIdx.x; i < F1 * C2; i += blockDim.x) w2s[i] = W2[i];
    if (threadIdx.x < C2) { as_s[threadIdx.x] = a_src[threadIdx.x]; ad_s[threadIdx.x] = a_dst[threadIdx.x]; }
    __syncthreads();

    int n = blockIdx.x * blockDim.x + threadIdx.x;
    if (n >= N_NODES) return;
    float acc[C2];
#pragma unroll
    for (int c = 0; c < C2; ++c) acc[c] = 0.f;
    const float* hp = hin + (size_t)n * F1;
    for (int k = 0; k < F1; k += 4) {
        const float4 hv = *(const float4*)(hp + k);
#pragma unroll
        for (int c = 0; c < C2; ++c) {
            acc[c] = fmaf(hv.x, w2s[(k + 0) * C2 + c], acc[c]);
            acc[c] = fmaf(hv.y, w2s[(k + 1) * C2 + c], acc[c]);
            acc[c] = fmaf(hv.z, w2s[(k + 2) * C2 + c], acc[c]);
            acc[c] = fmaf(hv.w, w2s[(k + 3) * C2 + c], acc[c]);
        }
    }
    float s = 0.f, d = 0.f;
#pragma unroll
    for (int c = 0; c < C2; ++c) {
        s = fmaf(acc[c], as_s[c], s);
        d = fmaf(acc[c], ad_s[c], d);
    }
    float4* o = (float4*)(h2p + (size_t)n * 8);
    o[0] = make_float4(acc[0], acc[1], acc[2], acc[3]);
    o[1] = make_float4(acc[4], acc[5], acc[6], 0.f);
    as2[n] = s;
    ad2[n] = d;
}

// ---------------- layer 2 aggregation + bias + log_softmax (no-max) ----------
__global__ __launch_bounds__(256) void agg2_kernel(
    const int* __restrict__ rowptr, const int* __restrict__ col,
    const float* __restrict__ h2p, const float* __restrict__ as2,
    const float* __restrict__ ad2, const float* __restrict__ b2,
    float* __restrict__ out)
{
    const int gq = (blockIdx.x * 256 + threadIdx.x) >> 2;   // node
    const int q = threadIdx.x & 3;
    if (gq >= N_NODES) return;
    const int r0 = rowptr[gq], r1 = rowptr[gq + 1];
    const float adn = ad2[gq];

    float denom = 0.f;
    float a0 = 0, a1 = 0, a2 = 0, a3 = 0, a4 = 0, a5 = 0, a6 = 0;
    for (int j = r0 + q; j < r1; j += 4) {
        const int s = col[j];
        float e = as2[s] + adn;
        e = fmaxf(e, 0.2f * e);
        const float ex = __expf(e);
        const float4 va = *(const float4*)(h2p + (size_t)s * 8);
        const float4 vb = *(const float4*)(h2p + (size_t)s * 8 + 4);
        denom += ex;
        a0 = fmaf(ex, va.x, a0); a1 = fmaf(ex, va.y, a1);
        a2 = fmaf(ex, va.z, a2); a3 = fmaf(ex, va.w, a3);
        a4 = fmaf(ex, vb.x, a4); a5 = fmaf(ex, vb.y, a5);
        a6 = fmaf(ex, vb.z, a6);
    }
#pragma unroll
    for (int d = 1; d < 4; d <<= 1) {
        denom += __shfl_xor(denom, d);
        a0 += __shfl_xor(a0, d); a1 += __shfl_xor(a1, d);
        a2 += __shfl_xor(a2, d); a3 += __shfl_xor(a3, d);
        a4 += __shfl_xor(a4, d); a5 += __shfl_xor(a5, d);
        a6 += __shfl_xor(a6, d);
    }
    const float inv = 1.f / denom;
    float v0 = a0 * inv + b2[0], v1 = a1 * inv + b2[1];
    float v2 = a2 * inv + b2[2], v3 = a3 * inv + b2[3];
    float v4 = a4 * inv + b2[4], v5 = a5 * inv + b2[5];
    float v6 = a6 * inv + b2[6];
    float mx = fmaxf(fmaxf(fmaxf(v0, v1), fmaxf(v2, v3)), fmaxf(fmaxf(v4, v5), v6));
    const float se = __expf(v0 - mx) + __expf(v1 - mx) + __expf(v2 - mx) +
                     __expf(v3 - mx) + __expf(v4 - mx) + __expf(v5 - mx) +
                     __expf(v6 - mx);
    const float lse = __logf(se) + mx;
    const float wa = (q == 0) ? v0 : (q == 1) ? v1 : (q == 2) ? v2 : v3;
    const float wb = (q == 0) ? v4 : (q == 1) ? v5 : v6;
    out[gq * C2 + q] = wa - lse;
    if (q < 3) out[gq * C2 + q + 4] = wb - lse;
}

extern "C" void kernel_launch(void* const* d_in, const int* in_sizes, int n_in,
                              void* d_out, int out_size, void* d_ws, size_t ws_size,
                              hipStream_t stream) {
    const float* x      = (const float*)d_in[0];
    const int*   ei     = (const int*)  d_in[1];
    const float* W1     = (const float*)d_in[2];
    const float* a_src1 = (const float*)d_in[3];
    const float* a_dst1 = (const float*)d_in[4];
    const float* b1     = (const float*)d_in[5];
    const float* W2     = (const float*)d_in[6];
    const float* a_src2 = (const float*)d_in[7];
    const float* a_dst2 = (const float*)d_in[8];
    const float* b2     = (const float*)d_in[9];
    float* out = (float*)d_out;

    char* ws = (char*)d_ws;
    size_t off = 0;
    auto alloc = [&](size_t bytes) -> void* {
        void* p = ws + off;
        off += (bytes + 255) & ~(size_t)255;
        return p;
    };
    int*    rowptr  = (int*)   alloc((N_NODES + 1) * sizeof(int));
    int*    boff    = (int*)   alloc((size_t)(NB + 1) * sizeof(int));
    int*    cntmat  = (int*)   alloc((size_t)FB * NB * sizeof(int));
    int*    basemat = (int*)   alloc((size_t)FB * NB * sizeof(int));
    int*    colidx  = (int*)   alloc((size_t)ET * sizeof(int));
    short*  wpk     = (short*) alloc((size_t)32768 * sizeof(short));
    __half* h1      = (__half*)alloc((size_t)N_NODES * F1 * sizeof(__half));
    float*  as1     = (float*) alloc((size_t)N_NODES * H1 * sizeof(float));
    float*  ad1     = (float*) alloc((size_t)N_NODES * H1 * sizeof(float));
    float*  hout1   = (float*) alloc((size_t)N_NODES * F1 * sizeof(float));
    float*  h2p     = (float*) alloc((size_t)N_NODES * 8 * sizeof(float));
    float*  as2     = (float*) alloc((size_t)N_NODES * sizeof(float));
    float*  ad2     = (float*) alloc((size_t)N_NODES * sizeof(float));
    // ebuf aliases hout1 (hout1 is dead until agg1, which runs after bucket_csr)
    unsigned int* ebuf = (unsigned int*)hout1;

    wprep<<<128, 256, 0, stream>>>(W1, wpk);
    fill_count<<<FB, 1024, 0, stream>>>(ei, cntmat);
    scan2<<<1, 1024, 0, stream>>>(cntmat, boff, basemat, rowptr);
    fill_scatter<<<FB, 1024, 0, stream>>>(ei, basemat, ebuf);
    bucket_csr<<<NB, 256, 0, stream>>>(boff, ebuf, colidx, rowptr);
    gemm1_kernel<<<(N_NODES + 63) / 64, 256, 0, stream>>>(x, wpk, a_src1, a_dst1, h1, as1, ad1);
    agg1_kernel<<<(N_NODES + 3) / 4, 256, 0, stream>>>(rowptr, colidx, h1, as1, ad1, b1, hout1);
    gemm2_kernel<<<(N_NODES + 255) / 256, 256, 0, stream>>>(hout1, W2, a_src2, a_dst2, h2p, as2, ad2);
    agg2_kernel<<<(N_NODES * 4 + 255) / 256, 256, 0, stream>>>(rowptr, colidx, h2p, as2, ad2, b2, out);
}

// Round 11
// 384.642 us; speedup vs baseline: 2.6256x; 1.0781x over previous
//
#include <hip/hip_runtime.h>
#include <hip/hip_bf16.h>
#include <hip/hip_fp16.h>

#define N_NODES 100000
#define N_EDGES 3200000
#define ET (N_EDGES + N_NODES)   // edges + self loops
#define F_IN 500
#define H1 8
#define C1 8
#define F1 64                    // H1*C1
#define C2 7

#define BSH 6                    // 64 nodes per bucket
#define NB ((N_NODES + 63) / 64) // 1563
#define CAP 6144                 // LDS edge capacity per bucket (avg ~2111)
#define FB 64                    // partition blocks
#define FCHUNK ((ET + FB - 1) / FB)

typedef __attribute__((ext_vector_type(8))) short short8;
typedef __attribute__((ext_vector_type(4))) float f32x4;

__device__ __forceinline__ unsigned short f2bf(float f) {
    const unsigned u = __float_as_uint(f);
    return (unsigned short)((u + 0x7FFFu + ((u >> 16) & 1u)) >> 16);
}

// ---------------- CSR build: atomic-free 3-phase partition ----------------
__global__ __launch_bounds__(1024) void fill_count(const int* __restrict__ ei,
                                                   int* __restrict__ cntmat) {
    __shared__ int hist[NB];
    const int t = threadIdx.x, blk = blockIdx.x;
    for (int i = t; i < NB; i += 1024) hist[i] = 0;
    __syncthreads();
    const int s0 = blk * FCHUNK;
    const int s1 = min(s0 + FCHUNK, ET);
    for (int i = s0 + t; i < s1; i += 1024) {
        const int dst = (i < N_EDGES) ? ei[N_EDGES + i] : (i - N_EDGES);
        atomicAdd(&hist[dst >> BSH], 1);
    }
    __syncthreads();
    int* row = cntmat + (size_t)blk * NB;
    for (int i = t; i < NB; i += 1024) row[i] = hist[i];
}

__global__ __launch_bounds__(1024) void scan2(const int* __restrict__ cntmat,
                                              int* __restrict__ boff,
                                              int* __restrict__ basemat,
                                              int* __restrict__ rowptr) {
    __shared__ int tot[2048];
    __shared__ int wsum[16];
    const int t = threadIdx.x;
    const int lane = t & 63;
    const int w = t >> 6;
    for (int b = t; b < 2048; b += 1024) {
        int s = 0;
        if (b < NB)
            for (int j = 0; j < FB; ++j) s += cntmat[(size_t)j * NB + b];
        tot[b] = s;
    }
    __syncthreads();
    int running = 0;
    for (int t0 = 0; t0 < 2048; t0 += 1024) {
        const int v = tot[t0 + t];
        int sc = v;
#pragma unroll
        for (int d = 1; d < 64; d <<= 1) {
            int u = __shfl_up(sc, d);
            if (lane >= d) sc += u;
        }
        if (lane == 63) wsum[w] = sc;
        __syncthreads();
        if (t < 16) {
            int ws = wsum[t];
#pragma unroll
            for (int d = 1; d < 16; d <<= 1) {
                int u = __shfl_up(ws, d);
                if (t >= d) ws += u;
            }
            wsum[t] = ws;
        }
        __syncthreads();
        const int excl = running + (w ? wsum[w - 1] : 0) + sc - v;
        if (t0 + t < NB) boff[t0 + t] = excl;
        const int tt = wsum[15];
        __syncthreads();
        tot[t0 + t] = excl;
        running += tt;
    }
    if (t == 0) {
        boff[NB] = running;            // == ET
        rowptr[N_NODES] = running;
    }
    __syncthreads();
    for (int b = t; b < NB; b += 1024) {
        int run = tot[b];
        for (int j = 0; j < FB; ++j) {
            basemat[(size_t)j * NB + b] = run;
            run += cntmat[(size_t)j * NB + b];
        }
    }
}

__global__ __launch_bounds__(1024) void fill_scatter(const int* __restrict__ ei,
                                                     const int* __restrict__ basemat,
                                                     unsigned int* __restrict__ ebuf) {
    __shared__ int cur[NB];
    const int t = threadIdx.x, blk = blockIdx.x;
    const int* row = basemat + (size_t)blk * NB;
    for (int i = t; i < NB; i += 1024) cur[i] = row[i];
    __syncthreads();
    const int s0 = blk * FCHUNK;
    const int s1 = min(s0 + FCHUNK, ET);
    for (int i = s0 + t; i < s1; i += 1024) {
        int src, dst;
        if (i < N_EDGES) { src = ei[i]; dst = ei[N_EDGES + i]; }
        else             { src = dst = i - N_EDGES; }
        const int b = dst >> BSH;
        const int p = atomicAdd(&cur[b], 1);
        ebuf[p] = (unsigned)src | ((unsigned)(dst & 63) << 17);
    }
}

__global__ __launch_bounds__(256) void bucket_csr(const int* __restrict__ boff,
                                                  const unsigned int* __restrict__ ebuf,
                                                  int* __restrict__ col,
                                                  int* __restrict__ rowptr) {
    __shared__ unsigned int ebs[CAP];
    __shared__ int colb[CAP];
    __shared__ int hist[64], curs[64];
    const int b = blockIdx.x, t = threadIdx.x;
    const int e0 = boff[b], e1 = boff[b + 1];
    const int cnt = e1 - e0;
    if (t < 64) hist[t] = 0;
    __syncthreads();

    if (cnt <= CAP) {
        for (int i = t; i < cnt; i += 256) {
            const unsigned v = ebuf[e0 + i];
            ebs[i] = v;
            atomicAdd(&hist[v >> 17], 1);
        }
        __syncthreads();
        if (t < 64) {
            const int v = hist[t];
            int sc = v;
#pragma unroll
            for (int d = 1; d < 64; d <<= 1) {
                int u = __shfl_up(sc, d);
                if (t >= d) sc += u;
            }
            const int excl = sc - v;
            curs[t] = excl;
            const int n = (b << BSH) + t;
            if (n < N_NODES) rowptr[n] = e0 + excl;
        }
        __syncthreads();
        for (int i = t; i < cnt; i += 256) {
            const unsigned v = ebs[i];
            const int p = atomicAdd(&curs[v >> 17], 1);
            colb[p] = (int)(v & 0x1FFFFu);
        }
        __syncthreads();
        for (int i = t; i < cnt; i += 256) col[e0 + i] = colb[i];
    } else {
        for (int i = t; i < cnt; i += 256) atomicAdd(&hist[ebuf[e0 + i] >> 17], 1);
        __syncthreads();
        if (t < 64) {
            const int v = hist[t];
            int sc = v;
#pragma unroll
            for (int d = 1; d < 64; d <<= 1) {
                int u = __shfl_up(sc, d);
                if (t >= d) sc += u;
            }
            const int excl = sc - v;
            curs[t] = excl;
            const int n = (b << BSH) + t;
            if (n < N_NODES) rowptr[n] = e0 + excl;
        }
        __syncthreads();
        for (int i = t; i < cnt; i += 256) {
            const unsigned v = ebuf[e0 + i];
            const int p = atomicAdd(&curs[v >> 17], 1);
            col[e0 + p] = (int)(v & 0x1FFFFu);
        }
    }
}

// ---------------- W prep: W1[500][64] -> bf16 fragment-packed wpk ----------------
__global__ __launch_bounds__(256) void wprep(const float* __restrict__ W1,
                                             short* __restrict__ wpk) {
    const int idx = blockIdx.x * 256 + threadIdx.x;
    if (idx >= 32768) return;
    const int j = idx & 7;
    const int l = (idx >> 3) & 63;
    const int f = (idx >> 9) & 3;
    const int ks = idx >> 11;
    const int k = ks * 32 + ((l >> 4) << 3) + j;
    const int col = f * 16 + (l & 15);
    const float fv = (k < F_IN) ? W1[k * F1 + col] : 0.f;
    wpk[idx] = (short)f2bf(fv);
}

// ---------------- layer 1 GEMM: MFMA, split-A (hi+lo) x bf16-W ----------------
__global__ __launch_bounds__(256) void gemm1_kernel(
    const float* __restrict__ x, const short* __restrict__ wpk,
    const float* __restrict__ a_src, const float* __restrict__ a_dst,
    __half* __restrict__ h1, float* __restrict__ as1, float* __restrict__ ad1)
{
    const int t = threadIdx.x;
    const int l = t & 63;
    const int w = t >> 6;
    const int row0 = blockIdx.x * 64 + w * 16;
    const int r = l & 15;
    const int koff = (l >> 4) * 8;
    const float* __restrict__ xp =
        x + (size_t)min(row0 + r, N_NODES - 1) * F_IN + koff;
    const short* __restrict__ wl = wpk + (l << 3);

    f32x4 acc[4];
#pragma unroll
    for (int f = 0; f < 4; ++f) acc[f] = (f32x4){0.f, 0.f, 0.f, 0.f};

    float4 va = *(const float4*)(xp);
    float4 vb = *(const float4*)(xp + 4);
    short8 bcur[4];
#pragma unroll
    for (int f = 0; f < 4; ++f)
        bcur[f] = *(const short8*)(wl + (f << 9));

    for (int ks = 0; ks < 16; ++ks) {
        float v[8];
        v[0] = va.x; v[1] = va.y; v[2] = va.z; v[3] = va.w;
        v[4] = vb.x; v[5] = vb.y; v[6] = vb.z; v[7] = vb.w;
        if (ks < 14) {
            va = *(const float4*)(xp + (ks + 1) * 32);
            vb = *(const float4*)(xp + (ks + 1) * 32 + 4);
        } else if (ks == 14) {
            float tv[8];
#pragma unroll
            for (int j = 0; j < 8; ++j)
                tv[j] = (koff + j < 20) ? xp[480 + j] : 0.f;
            va = make_float4(tv[0], tv[1], tv[2], tv[3]);
            vb = make_float4(tv[4], tv[5], tv[6], tv[7]);
        }
        short8 bnext[4];
        if (ks < 15) {
#pragma unroll
            for (int f = 0; f < 4; ++f)
                bnext[f] = *(const short8*)(wl + (((ks + 1) * 4 + f) << 9));
        }
        short8 ah, al;
#pragma unroll
        for (int j = 0; j < 8; ++j) {
            const unsigned short h = f2bf(v[j]);
            ah[j] = (short)h;
            al[j] = (short)f2bf(v[j] - __uint_as_float((unsigned)h << 16));
        }
#pragma unroll
        for (int f = 0; f < 4; ++f) {
            acc[f] = __builtin_amdgcn_mfma_f32_16x16x32_bf16(ah, bcur[f], acc[f], 0, 0, 0);
            acc[f] = __builtin_amdgcn_mfma_f32_16x16x32_bf16(al, bcur[f], acc[f], 0, 0, 0);
        }
        if (ks < 15) {
#pragma unroll
            for (int f = 0; f < 4; ++f) bcur[f] = bnext[f];
        }
    }

    // epilogue: D[row][col], row = row0 + (l>>4)*4 + reg, col = f*16 + (l&15)
    const int g = l >> 4;
    const int p = r >> 3;
    float asv[4], adv[4];
#pragma unroll
    for (int f = 0; f < 4; ++f) {
        asv[f] = a_src[f * 16 + r];
        adv[f] = a_dst[f * 16 + r];
    }
#pragma unroll
    for (int f = 0; f < 4; ++f) {
#pragma unroll
        for (int reg = 0; reg < 4; ++reg) {
            const int row = row0 + g * 4 + reg;
            const float hv = acc[f][reg];
            if (row < N_NODES)
                h1[(size_t)row * F1 + f * 16 + r] = __float2half(hv);
            float ps = hv * asv[f];
            float pd = hv * adv[f];
            ps += __shfl_xor(ps, 1); ps += __shfl_xor(ps, 2); ps += __shfl_xor(ps, 4);
            pd += __shfl_xor(pd, 1); pd += __shfl_xor(pd, 2); pd += __shfl_xor(pd, 4);
            if ((l & 7) == 0 && row < N_NODES) {
                as1[row * H1 + f * 2 + p] = ps;
                ad1[row * H1 + f * 2 + p] = pd;
            }
        }
    }
}

// ---------------- layer 1 aggregation: wave per node, 8x8 scheme ----------
// Chunk of 8 edges: lane l computes e/exp for (edge l&7, head l>>3) ONCE
// (was 8x redundant). Inner loop: p via bpermute from lane (l&56)+j,
// s_j via readlane (SGPR -> saddr h1 load with const voffset l*2).
__global__ __launch_bounds__(256) void agg1_kernel(
    const int* __restrict__ rowptr, const int* __restrict__ col,
    const __half* __restrict__ h1, const float* __restrict__ as1,
    const float* __restrict__ ad1, const float* __restrict__ b1,
    float* __restrict__ hout)
{
    const int l = threadIdx.x & 63;
    const int n = (blockIdx.x << 2) + (threadIdx.x >> 6);
    if (n >= N_NODES) return;
    const int jsub = l & 7;          // lane's edge slot in chunk
    const int hsub = l >> 3;         // lane's head for e-compute
    const int pbase = l & 56;        // p for (edge j, my head) lives in lane pbase+j
    const int r0 = rowptr[n], r1 = rowptr[n + 1];
    const float adh = ad1[(n << 3) + hsub];

    float denom = 0.f, acc = 0.f;
    int j0 = r0;
    // full chunks: 8 valid edges, no guards
    for (; j0 + 8 <= r1; j0 += 8) {
        const int s_l = col[j0 + jsub];
        float e = as1[(s_l << 3) + hsub] + adh;
        e = fmaxf(e, 0.2f * e);
        const float p_l = __expf(e);
#pragma unroll
        for (int j = 0; j < 8; ++j) {
            const float p = __shfl(p_l, pbase + j);
            const int s_j = __builtin_amdgcn_readlane(s_l, j);
            const float v = __half2float(h1[((size_t)(unsigned)s_j << 6) + l]);
            denom += p;
            acc = fmaf(p, v, acc);
        }
    }
    // tail chunk: guarded (wave-uniform branches)
    if (j0 < r1) {
        const int jc = min(j0 + jsub, r1 - 1);
        const int s_l = col[jc];
        float e = as1[(s_l << 3) + hsub] + adh;
        e = fmaxf(e, 0.2f * e);
        const float p_l = __expf(e);
#pragma unroll
        for (int j = 0; j < 8; ++j) {
            if (j0 + j < r1) {
                const float p = __shfl(p_l, pbase + j);
                const int s_j = __builtin_amdgcn_readlane(s_l, j);
                const float v = __half2float(h1[((size_t)(unsigned)s_j << 6) + l]);
                denom += p;
                acc = fmaf(p, v, acc);
            }
        }
    }
    hout[(n << 6) + l] = acc / denom + b1[l];
}

// ---------------- layer 2 GEMM + attention coefficients ----------------
__global__ __launch_bounds__(256) void gemm2_kernel(
    const float* __restrict__ hin, const float* __restrict__ W2,
    const float* __restrict__ a_src, const float* __restrict__ a_dst,
    float* __restrict__ h2p, float* __restrict__ as2, float* __restrict__ ad2)
{
    __shared__ float w2s[F1 * C2];
    __shared__ float as_s[C2], ad_s[C2];
    for (int i = threadIdx.x; i < F1 * C2; i += blockDim.x) w2s[i] = W2[i];
    if (threadIdx.x < C2) { as_s[threadIdx.x] = a_src[threadIdx.x]; ad_s[threadIdx.x] = a_dst[threadIdx.x]; }
    __syncthreads();

    int n = blockIdx.x * blockDim.x + threadIdx.x;
    if (n >= N_NODES) return;
    float acc[C2];
#pragma unroll
    for (int c = 0; c < C2; ++c) acc[c] = 0.f;
    const float* hp = hin + (size_t)n * F1;
    for (int k = 0; k < F1; k += 4) {
        const float4 hv = *(const float4*)(hp + k);
#pragma unroll
        for (int c = 0; c < C2; ++c) {
            acc[c] = fmaf(hv.x, w2s[(k + 0) * C2 + c], acc[c]);
            acc[c] = fmaf(hv.y, w2s[(k + 1) * C2 + c], acc[c]);
            acc[c] = fmaf(hv.z, w2s[(k + 2) * C2 + c], acc[c]);
            acc[c] = fmaf(hv.w, w2s[(k + 3) * C2 + c], acc[c]);
        }
    }
    float s = 0.f, d = 0.f;
#pragma unroll
    for (int c = 0; c < C2; ++c) {
        s = fmaf(acc[c], as_s[c], s);
        d = fmaf(acc[c], ad_s[c], d);
    }
    float4* o = (float4*)(h2p + (size_t)n * 8);
    o[0] = make_float4(acc[0], acc[1], acc[2], acc[3]);
    o[1] = make_float4(acc[4], acc[5], acc[6], 0.f);
    as2[n] = s;
    ad2[n] = d;
}

// ---------------- layer 2 aggregation + bias + log_softmax (no-max) ----------
__global__ __launch_bounds__(256) void agg2_kernel(
    const int* __restrict__ rowptr, const int* __restrict__ col,
    const float* __restrict__ h2p, const float* __restrict__ as2,
    const float* __restrict__ ad2, const float* __restrict__ b2,
    float* __restrict__ out)
{
    const int gq = (blockIdx.x * 256 + threadIdx.x) >> 2;   // node
    const int q = threadIdx.x & 3;
    if (gq >= N_NODES) return;
    const int r0 = rowptr[gq], r1 = rowptr[gq + 1];
    const float adn = ad2[gq];

    float denom = 0.f;
    float a0 = 0, a1 = 0, a2 = 0, a3 = 0, a4 = 0, a5 = 0, a6 = 0;
    for (int j = r0 + q; j < r1; j += 4) {
        const int s = col[j];
        float e = as2[s] + adn;
        e = fmaxf(e, 0.2f * e);
        const float ex = __expf(e);
        const float4 va = *(const float4*)(h2p + (size_t)s * 8);
        const float4 vb = *(const float4*)(h2p + (size_t)s * 8 + 4);
        denom += ex;
        a0 = fmaf(ex, va.x, a0); a1 = fmaf(ex, va.y, a1);
        a2 = fmaf(ex, va.z, a2); a3 = fmaf(ex, va.w, a3);
        a4 = fmaf(ex, vb.x, a4); a5 = fmaf(ex, vb.y, a5);
        a6 = fmaf(ex, vb.z, a6);
    }
#pragma unroll
    for (int d = 1; d < 4; d <<= 1) {
        denom += __shfl_xor(denom, d);
        a0 += __shfl_xor(a0, d); a1 += __shfl_xor(a1, d);
        a2 += __shfl_xor(a2, d); a3 += __shfl_xor(a3, d);
        a4 += __shfl_xor(a4, d); a5 += __shfl_xor(a5, d);
        a6 += __shfl_xor(a6, d);
    }
    const float inv = 1.f / denom;
    float v0 = a0 * inv + b2[0], v1 = a1 * inv + b2[1];
    float v2 = a2 * inv + b2[2], v3 = a3 * inv + b2[3];
    float v4 = a4 * inv + b2[4], v5 = a5 * inv + b2[5];
    float v6 = a6 * inv + b2[6];
    float mx = fmaxf(fmaxf(fmaxf(v0, v1), fmaxf(v2, v3)), fmaxf(fmaxf(v4, v5), v6));
    const float se = __expf(v0 - mx) + __expf(v1 - mx) + __expf(v2 - mx) +
                     __expf(v3 - mx) + __expf(v4 - mx) + __expf(v5 - mx) +
                     __expf(v6 - mx);
    const float lse = __logf(se) + mx;
    const float wa = (q == 0) ? v0 : (q == 1) ? v1 : (q == 2) ? v2 : v3;
    const float wb = (q == 0) ? v4 : (q == 1) ? v5 : v6;
    out[gq * C2 + q] = wa - lse;
    if (q < 3) out[gq * C2 + q + 4] = wb - lse;
}

extern "C" void kernel_launch(void* const* d_in, const int* in_sizes, int n_in,
                              void* d_out, int out_size, void* d_ws, size_t ws_size,
                              hipStream_t stream) {
    const float* x      = (const float*)d_in[0];
    const int*   ei     = (const int*)  d_in[1];
    const float* W1     = (const float*)d_in[2];
    const float* a_src1 = (const float*)d_in[3];
    const float* a_dst1 = (const float*)d_in[4];
    const float* b1     = (const float*)d_in[5];
    const float* W2     = (const float*)d_in[6];
    const float* a_src2 = (const float*)d_in[7];
    const float* a_dst2 = (const float*)d_in[8];
    const float* b2     = (const float*)d_in[9];
    float* out = (float*)d_out;

    char* ws = (char*)d_ws;
    size_t off = 0;
    auto alloc = [&](size_t bytes) -> void* {
        void* p = ws + off;
        off += (bytes + 255) & ~(size_t)255;
        return p;
    };
    int*    rowptr  = (int*)   alloc((N_NODES + 1) * sizeof(int));
    int*    boff    = (int*)   alloc((size_t)(NB + 1) * sizeof(int));
    int*    cntmat  = (int*)   alloc((size_t)FB * NB * sizeof(int));
    int*    basemat = (int*)   alloc((size_t)FB * NB * sizeof(int));
    int*    colidx  = (int*)   alloc((size_t)ET * sizeof(int));
    short*  wpk     = (short*) alloc((size_t)32768 * sizeof(short));
    __half* h1      = (__half*)alloc((size_t)N_NODES * F1 * sizeof(__half));
    float*  as1     = (float*) alloc((size_t)N_NODES * H1 * sizeof(float));
    float*  ad1     = (float*) alloc((size_t)N_NODES * H1 * sizeof(float));
    float*  hout1   = (float*) alloc((size_t)N_NODES * F1 * sizeof(float));
    float*  h2p     = (float*) alloc((size_t)N_NODES * 8 * sizeof(float));
    float*  as2     = (float*) alloc((size_t)N_NODES * sizeof(float));
    float*  ad2     = (float*) alloc((size_t)N_NODES * sizeof(float));
    // ebuf aliases hout1 (hout1 is dead until agg1, which runs after bucket_csr)
    unsigned int* ebuf = (unsigned int*)hout1;

    wprep<<<128, 256, 0, stream>>>(W1, wpk);
    fill_count<<<FB, 1024, 0, stream>>>(ei, cntmat);
    scan2<<<1, 1024, 0, stream>>>(cntmat, boff, basemat, rowptr);
    fill_scatter<<<FB, 1024, 0, stream>>>(ei, basemat, ebuf);
    bucket_csr<<<NB, 256, 0, stream>>>(boff, ebuf, colidx, rowptr);
    gemm1_kernel<<<(N_NODES + 63) / 64, 256, 0, stream>>>(x, wpk, a_src1, a_dst1, h1, as1, ad1);
    agg1_kernel<<<(N_NODES + 3) / 4, 256, 0, stream>>>(rowptr, colidx, h1, as1, ad1, b1, hout1);
    gemm2_kernel<<<(N_NODES + 255) / 256, 256, 0, stream>>>(hout1, W2, a_src2, a_dst2, h2p, as2, ad2);
    agg2_kernel<<<(N_NODES * 4 + 255) / 256, 256, 0, stream>>>(rowptr, colidx, h2p, as2, ad2, b2, out);
}